// Round 1
// baseline (1282.019 us; speedup 1.0000x reference)
//
#include <hip/hip_runtime.h>
#include <hip/hip_bf16.h>
#include <math.h>

#define D_LLM 768
#define DKH   1024   // d_keys * n_heads = 128*8
#define NH    8
#define DK    128
#define S_LEN 1000
#define M_ROWS 12288 // B*N*T = 128*96
#define T_LEN 96
#define N_VARS 16

// ---------------- Wksum: Wksum[d][h] = sum_e Wk[d][h*128+e]; bksum[h] = sum_e bk ----------------
__global__ void wksum_kernel(const float* __restrict__ Wk, const float* __restrict__ bk,
                             float* __restrict__ Wksum, float* __restrict__ bksum) {
    int idx = blockIdx.x * 256 + threadIdx.x;
    if (idx < D_LLM * NH) {
        int d = idx / NH, h = idx % NH;
        float acc = 0.f;
        const float* p = Wk + (size_t)d * DKH + h * DK;
        #pragma unroll 8
        for (int e = 0; e < DK; ++e) acc += p[e];
        Wksum[d * NH + h] = acc;
    }
    if (idx < NH) {
        float acc = 0.f;
        const float* p = bk + idx * DK;
        for (int e = 0; e < DK; ++e) acc += p[e];
        bksum[idx] = acc;
    }
}

// ---------------- Ksum[h][s] = src[s,:] . Wksum[:,h] + bksum[h] ----------------
__global__ __launch_bounds__(256) void ksum_kernel(const float* __restrict__ src,
                                                   const float* __restrict__ Wksum,
                                                   const float* __restrict__ bksum,
                                                   float* __restrict__ Ksum) {
    int wave = blockIdx.x * 4 + (threadIdx.x >> 6);
    int lane = threadIdx.x & 63;
    if (wave >= S_LEN * NH) return;
    int s = wave / NH, h = wave % NH;
    float acc = 0.f;
    const float* sp = src + (size_t)s * D_LLM;
    for (int d = lane; d < D_LLM; d += 64) acc += sp[d] * Wksum[d * NH + h];
    #pragma unroll
    for (int off = 32; off > 0; off >>= 1) acc += __shfl_down(acc, off);
    if (lane == 0) Ksum[h * S_LEN + s] = acc + bksum[h];
}

// ---------------- per-head min/max of Ksum ----------------
__global__ __launch_bounds__(512) void kminmax_kernel(const float* __restrict__ Ksum,
                                                      float* __restrict__ mnmx) {
    int h = threadIdx.x >> 6, lane = threadIdx.x & 63;
    float mx = -1e30f, mn = 1e30f;
    for (int s = lane; s < S_LEN; s += 64) {
        float v = Ksum[h * S_LEN + s];
        mx = fmaxf(mx, v); mn = fminf(mn, v);
    }
    #pragma unroll
    for (int off = 32; off > 0; off >>= 1) {
        mx = fmaxf(mx, __shfl_down(mx, off));
        mn = fminf(mn, __shfl_down(mn, off));
    }
    if (lane == 0) { mnmx[h * 2] = mn; mnmx[h * 2 + 1] = mx; }
}

// ---------------- generic fp32 GEMM with bias: C[M,N] = A[M,K] @ B[K,N] + bias[N] ----------------
// Requires N % 64 == 0, K % 16 == 0. M arbitrary (guarded).
#define BM 64
#define BN 64
#define BK 16
__global__ __launch_bounds__(256) void gemm_bias_kernel(const float* __restrict__ A,
                                                        const float* __restrict__ B,
                                                        const float* __restrict__ bias,
                                                        float* __restrict__ C,
                                                        int M, int N, int K) {
    __shared__ float As[BK][BM + 1];
    __shared__ float Bs[BK][BN + 1];
    int tid = threadIdx.x;
    int tx = tid & 15, ty = tid >> 4;
    int row0 = blockIdx.y * BM + ty * 4;
    int col0 = blockIdx.x * BN + tx * 4;
    float acc[4][4] = {};
    // loader coords
    int fA = tid * 4;
    int a_m = fA >> 4;          // 0..63
    int a_k = fA & 15;          // 0,4,8,12
    int b_k = fA >> 6;          // 0..15
    int b_n = fA & 63;          // 0,4,...,60
    int a_row = blockIdx.y * BM + a_m;
    const float* Bcol = B + blockIdx.x * BN + b_n;
    for (int k0 = 0; k0 < K; k0 += BK) {
        float4 av = make_float4(0.f, 0.f, 0.f, 0.f);
        if (a_row < M) av = *(const float4*)(A + (size_t)a_row * K + k0 + a_k);
        As[a_k + 0][a_m] = av.x; As[a_k + 1][a_m] = av.y;
        As[a_k + 2][a_m] = av.z; As[a_k + 3][a_m] = av.w;
        float4 bv = *(const float4*)(Bcol + (size_t)(k0 + b_k) * N);
        Bs[b_k][b_n + 0] = bv.x; Bs[b_k][b_n + 1] = bv.y;
        Bs[b_k][b_n + 2] = bv.z; Bs[b_k][b_n + 3] = bv.w;
        __syncthreads();
        #pragma unroll
        for (int kk = 0; kk < BK; ++kk) {
            float a0 = As[kk][ty * 4 + 0], a1 = As[kk][ty * 4 + 1];
            float a2 = As[kk][ty * 4 + 2], a3 = As[kk][ty * 4 + 3];
            float b0 = Bs[kk][tx * 4 + 0], b1 = Bs[kk][tx * 4 + 1];
            float b2 = Bs[kk][tx * 4 + 2], b3 = Bs[kk][tx * 4 + 3];
            acc[0][0] += a0 * b0; acc[0][1] += a0 * b1; acc[0][2] += a0 * b2; acc[0][3] += a0 * b3;
            acc[1][0] += a1 * b0; acc[1][1] += a1 * b1; acc[1][2] += a1 * b2; acc[1][3] += a1 * b3;
            acc[2][0] += a2 * b0; acc[2][1] += a2 * b1; acc[2][2] += a2 * b2; acc[2][3] += a2 * b3;
            acc[3][0] += a3 * b0; acc[3][1] += a3 * b1; acc[3][2] += a3 * b2; acc[3][3] += a3 * b3;
        }
        __syncthreads();
    }
    #pragma unroll
    for (int i = 0; i < 4; ++i) {
        int r = row0 + i;
        if (r < M) {
            #pragma unroll
            for (int j = 0; j < 4; ++j) {
                C[(size_t)r * N + col0 + j] = acc[i][j] + bias[col0 + j];
            }
        }
    }
}

// ---------------- fused softmax + PV: attout[m][h*128+e] ----------------
// scores[m,h,s] = x_m * Ksum[h,s]; A = softmax_s; out = A @ V[:,h,:]
#define G 4
__global__ __launch_bounds__(128) void attn_kernel(const float* __restrict__ ts,     // [B=8][T=96][N=16]
                                                   const float* __restrict__ Ksum,   // [8][1000]
                                                   const float* __restrict__ mnmx,   // [8][2]
                                                   const float* __restrict__ V,      // [1000][1024]
                                                   float* __restrict__ attout) {     // [12288][1024]
    __shared__ float wlds[S_LEN][G];
    __shared__ float red[2][G];
    __shared__ float denl[G];
    int h = blockIdx.y;
    int m0 = blockIdx.x * G;
    int tid = threadIdx.x;

    float mn = mnmx[h * 2], mx = mnmx[h * 2 + 1];
    float x[G], mref[G];
    #pragma unroll
    for (int g = 0; g < G; ++g) {
        int m = m0 + g;
        int r = m / T_LEN, t = m % T_LEN;
        int b = r / N_VARS, n = r % N_VARS;
        float v = ts[((size_t)b * T_LEN + t) * N_VARS + n];
        if (isnan(v)) v = 0.f;
        x[g] = v * 0.08838834764831845f; // 1/sqrt(128)
        mref[g] = (x[g] >= 0.f) ? x[g] * mx : x[g] * mn;
    }

    float dpart[G] = {0.f, 0.f, 0.f, 0.f};
    for (int s = tid; s < S_LEN; s += 128) {
        float kv = Ksum[h * S_LEN + s];
        #pragma unroll
        for (int g = 0; g < G; ++g) {
            float w = __expf(x[g] * kv - mref[g]);
            wlds[s][g] = w;
            dpart[g] += w;
        }
    }
    #pragma unroll
    for (int off = 32; off > 0; off >>= 1) {
        #pragma unroll
        for (int g = 0; g < G; ++g) dpart[g] += __shfl_down(dpart[g], off);
    }
    int wv = tid >> 6, ln = tid & 63;
    if (ln == 0) {
        #pragma unroll
        for (int g = 0; g < G; ++g) red[wv][g] = dpart[g];
    }
    __syncthreads();
    if (tid == 0) {
        #pragma unroll
        for (int g = 0; g < G; ++g) denl[g] = red[0][g] + red[1][g];
    }
    __syncthreads();
    float inv[G];
    #pragma unroll
    for (int g = 0; g < G; ++g) inv[g] = 1.0f / denl[g];

    float acc[G] = {0.f, 0.f, 0.f, 0.f};
    const float* vp = V + h * DK + tid;
    #pragma unroll 4
    for (int s = 0; s < S_LEN; ++s) {
        float v = vp[(size_t)s * DKH];
        #pragma unroll
        for (int g = 0; g < G; ++g) acc[g] += wlds[s][g] * v;
    }
    #pragma unroll
    for (int g = 0; g < G; ++g) {
        int m = m0 + g;
        attout[(size_t)m * DKH + h * DK + tid] = acc[g] * inv[g];
    }
}

extern "C" void kernel_launch(void* const* d_in, const int* in_sizes, int n_in,
                              void* d_out, int out_size, void* d_ws, size_t ws_size,
                              hipStream_t stream) {
    const float* ts   = (const float*)d_in[0];
    const float* src  = (const float*)d_in[1];
    const float* vemb = (const float*)d_in[2];
    const float* Wk   = (const float*)d_in[3];
    const float* bk   = (const float*)d_in[4];
    const float* Wv   = (const float*)d_in[5];
    const float* bv   = (const float*)d_in[6];
    const float* Wo   = (const float*)d_in[7];
    const float* bo   = (const float*)d_in[8];
    float* out = (float*)d_out;

    // workspace layout (floats)
    float* ws = (float*)d_ws;
    float* V      = ws;                    // 1000*1024       = 1,024,000
    float* Ksum   = V + 1024000;           // 8*1000          = 8,000
    float* Wksum  = Ksum + 8000;           // 768*8           = 6,144
    float* bksum  = Wksum + 6144;          // 8
    float* mnmx   = bksum + 8;             // 16
    float* attout = ws + 1048576;          // 12288*1024      = 12,582,912

    // 1) Wksum / bksum
    wksum_kernel<<<(D_LLM * NH + 255) / 256, 256, 0, stream>>>(Wk, bk, Wksum, bksum);
    // 2) Ksum
    ksum_kernel<<<(S_LEN * NH + 3) / 4, 256, 0, stream>>>(src, Wksum, bksum, Ksum);
    // 3) min/max per head
    kminmax_kernel<<<1, 512, 0, stream>>>(Ksum, mnmx);
    // 4) V projection: [1000,768] @ [768,1024] + bv
    {
        dim3 grid(DKH / BN, (S_LEN + BM - 1) / BM);
        gemm_bias_kernel<<<grid, 256, 0, stream>>>(vemb, Wv, bv, V, S_LEN, DKH, D_LLM);
    }
    // 5) fused softmax + PV
    {
        dim3 grid(M_ROWS / G, NH);
        attn_kernel<<<grid, 128, 0, stream>>>(ts, Ksum, mnmx, V, attout);
    }
    // 6) output projection: [12288,1024] @ [1024,768] + bo
    {
        dim3 grid(D_LLM / BN, M_ROWS / BM);
        gemm_bias_kernel<<<grid, 256, 0, stream>>>(attout, Wo, bo, out, M_ROWS, D_LLM, DKH);
    }
}

// Round 2
// 306.581 us; speedup vs baseline: 4.1817x; 4.1817x over previous
//
#include <hip/hip_runtime.h>
#include <hip/hip_bf16.h>
#include <math.h>

#define D_LLM 768
#define DKH   1024   // d_keys * n_heads = 128*8
#define NH    8
#define DK    128
#define S_LEN 1000
#define S_PAD 1024
#define M_ROWS 12288 // B*N*T = 128*96
#define T_LEN 96
#define N_VARS 16

typedef __attribute__((ext_vector_type(8))) short short8;
typedef __attribute__((ext_vector_type(4))) float f32x4;

// ---------------- Wksum: Wksum[d][h] = sum_e Wk[d][h*128+e]; bksum[h] = sum_e bk ----------------
__global__ void wksum_kernel(const float* __restrict__ Wk, const float* __restrict__ bk,
                             float* __restrict__ Wksum, float* __restrict__ bksum) {
    int idx = blockIdx.x * 256 + threadIdx.x;
    if (idx < D_LLM * NH) {
        int d = idx / NH, h = idx % NH;
        float acc = 0.f;
        const float* p = Wk + (size_t)d * DKH + h * DK;
        #pragma unroll 8
        for (int e = 0; e < DK; ++e) acc += p[e];
        Wksum[d * NH + h] = acc;
    }
    if (idx < NH) {
        float acc = 0.f;
        const float* p = bk + idx * DK;
        for (int e = 0; e < DK; ++e) acc += p[e];
        bksum[idx] = acc;
    }
}

// ---------------- Kpad[h][s] = src[s,:] . Wksum[:,h] + bksum[h]  (s>=1000 -> 0) ----------------
__global__ __launch_bounds__(256) void ksum_kernel(const float* __restrict__ src,
                                                   const float* __restrict__ Wksum,
                                                   const float* __restrict__ bksum,
                                                   float* __restrict__ Kpad) {
    int wave = blockIdx.x * 4 + (threadIdx.x >> 6);
    int lane = threadIdx.x & 63;
    if (wave >= S_PAD * NH) return;
    int s = wave >> 3, h = wave & 7;
    if (s >= S_LEN) { if (lane == 0) Kpad[h * S_PAD + s] = 0.f; return; }
    float acc = 0.f;
    const float* sp = src + (size_t)s * D_LLM;
    for (int d = lane; d < D_LLM; d += 64) acc += sp[d] * Wksum[d * NH + h];
    #pragma unroll
    for (int off = 32; off > 0; off >>= 1) acc += __shfl_down(acc, off);
    if (lane == 0) Kpad[h * S_PAD + s] = acc + bksum[h];
}

// ---------------- per-head min/max of Kpad over s<1000 ----------------
__global__ __launch_bounds__(512) void kminmax_kernel(const float* __restrict__ Kpad,
                                                      float* __restrict__ mnmx) {
    int h = threadIdx.x >> 6, lane = threadIdx.x & 63;
    float mx = -1e30f, mn = 1e30f;
    for (int s = lane; s < S_LEN; s += 64) {
        float v = Kpad[h * S_PAD + s];
        mx = fmaxf(mx, v); mn = fminf(mn, v);
    }
    #pragma unroll
    for (int off = 32; off > 0; off >>= 1) {
        mx = fmaxf(mx, __shfl_down(mx, off));
        mn = fminf(mn, __shfl_down(mn, off));
    }
    if (lane == 0) { mnmx[h * 2] = mn; mnmx[h * 2 + 1] = mx; }
}

// ---------------- fp32 GEMM with bias: C[M,N] = A[M,K] @ B[K,N] + bias[N] (V projection) ----------------
#define BM 64
#define BN 64
#define BK 16
__global__ __launch_bounds__(256) void gemm_bias_kernel(const float* __restrict__ A,
                                                        const float* __restrict__ B,
                                                        const float* __restrict__ bias,
                                                        float* __restrict__ C,
                                                        int M, int N, int K) {
    __shared__ float As[BK][BM + 1];
    __shared__ float Bs[BK][BN + 1];
    int tid = threadIdx.x;
    int tx = tid & 15, ty = tid >> 4;
    int row0 = blockIdx.y * BM + ty * 4;
    int col0 = blockIdx.x * BN + tx * 4;
    float acc[4][4] = {};
    int fA = tid * 4;
    int a_m = fA >> 4;
    int a_k = fA & 15;
    int b_k = fA >> 6;
    int b_n = fA & 63;
    int a_row = blockIdx.y * BM + a_m;
    const float* Bcol = B + blockIdx.x * BN + b_n;
    for (int k0 = 0; k0 < K; k0 += BK) {
        float4 av = make_float4(0.f, 0.f, 0.f, 0.f);
        if (a_row < M) av = *(const float4*)(A + (size_t)a_row * K + k0 + a_k);
        As[a_k + 0][a_m] = av.x; As[a_k + 1][a_m] = av.y;
        As[a_k + 2][a_m] = av.z; As[a_k + 3][a_m] = av.w;
        float4 bv = *(const float4*)(Bcol + (size_t)(k0 + b_k) * N);
        Bs[b_k][b_n + 0] = bv.x; Bs[b_k][b_n + 1] = bv.y;
        Bs[b_k][b_n + 2] = bv.z; Bs[b_k][b_n + 3] = bv.w;
        __syncthreads();
        #pragma unroll
        for (int kk = 0; kk < BK; ++kk) {
            float a0 = As[kk][ty * 4 + 0], a1 = As[kk][ty * 4 + 1];
            float a2 = As[kk][ty * 4 + 2], a3 = As[kk][ty * 4 + 3];
            float b0 = Bs[kk][tx * 4 + 0], b1 = Bs[kk][tx * 4 + 1];
            float b2 = Bs[kk][tx * 4 + 2], b3 = Bs[kk][tx * 4 + 3];
            acc[0][0] += a0 * b0; acc[0][1] += a0 * b1; acc[0][2] += a0 * b2; acc[0][3] += a0 * b3;
            acc[1][0] += a1 * b0; acc[1][1] += a1 * b1; acc[1][2] += a1 * b2; acc[1][3] += a1 * b3;
            acc[2][0] += a2 * b0; acc[2][1] += a2 * b1; acc[2][2] += a2 * b2; acc[2][3] += a2 * b3;
            acc[3][0] += a3 * b0; acc[3][1] += a3 * b1; acc[3][2] += a3 * b2; acc[3][3] += a3 * b3;
        }
        __syncthreads();
    }
    #pragma unroll
    for (int i = 0; i < 4; ++i) {
        int r = row0 + i;
        if (r < M) {
            #pragma unroll
            for (int j = 0; j < 4; ++j) {
                C[(size_t)r * N + col0 + j] = acc[i][j] + bias[col0 + j];
            }
        }
    }
}

// ---------------- transpose V fp32[1000][1024] -> Vt bf16[1024][1024] (s padded w/ 0) ----------------
__global__ __launch_bounds__(256) void vtrans_kernel(const float* __restrict__ V,
                                                     __hip_bfloat16* __restrict__ Vt) {
    __shared__ float t[32][33];
    int tx = threadIdx.x & 31, ty = threadIdx.x >> 5;  // ty 0..7
    int s0 = blockIdx.x * 32, c0 = blockIdx.y * 32;
    #pragma unroll
    for (int p = 0; p < 4; ++p) {
        int s = s0 + ty + p * 8;
        t[ty + p * 8][tx] = (s < S_LEN) ? V[(size_t)s * DKH + c0 + tx] : 0.f;
    }
    __syncthreads();
    #pragma unroll
    for (int p = 0; p < 4; ++p) {
        int c = c0 + ty + p * 8;
        Vt[(size_t)c * S_PAD + s0 + tx] = __float2bfloat16(t[tx][ty + p * 8]);
    }
}

// ---------------- transpose Wo fp32[1024][768] -> Wot bf16[768][1024] ----------------
__global__ __launch_bounds__(256) void wtrans_kernel(const float* __restrict__ Wo,
                                                     __hip_bfloat16* __restrict__ Wot) {
    __shared__ float t[32][33];
    int tx = threadIdx.x & 31, ty = threadIdx.x >> 5;
    int k0 = blockIdx.x * 32, n0 = blockIdx.y * 32;
    #pragma unroll
    for (int p = 0; p < 4; ++p) {
        int k = k0 + ty + p * 8;
        t[ty + p * 8][tx] = Wo[(size_t)k * D_LLM + n0 + tx];
    }
    __syncthreads();
    #pragma unroll
    for (int p = 0; p < 4; ++p) {
        int n = n0 + ty + p * 8;
        Wot[(size_t)n * DKH + k0 + tx] = __float2bfloat16(t[tx][ty + p * 8]);
    }
}

// ---------------- fused softmax + PV via MFMA ----------------
// wave: 32 rows (2 m-tiles) x 1 head, full e=128 (8 e-tiles), K-loop over s (step 32)
__global__ __launch_bounds__(256) void attn_mfma_kernel(const float* __restrict__ ts,
                                                        const float* __restrict__ Kpad,
                                                        const float* __restrict__ mnmx,
                                                        const __hip_bfloat16* __restrict__ Vt,
                                                        __hip_bfloat16* __restrict__ attB) {
    int lane = threadIdx.x & 63;
    int wg = blockIdx.x * 4 + (threadIdx.x >> 6);
    int h = wg & 7;
    int p = wg >> 3;            // 0..383
    int m0 = p * 32;

    float mn = mnmx[h * 2], mx = mnmx[h * 2 + 1];
    float x2[2], mref2[2];
    #pragma unroll
    for (int r = 0; r < 2; ++r) {
        int m = m0 + r * 16 + (lane & 15);
        int t = m % T_LEN;
        int rr = m / T_LEN;
        int b = rr >> 4, n = rr & 15;
        float v = ts[((size_t)b * T_LEN + t) * N_VARS + n];
        if (v != v) v = 0.f;
        float xs = v * 0.08838834764831845f;  // 1/sqrt(128)
        x2[r] = xs * 1.44269504088896f;       // /ln2 for exp2
        mref2[r] = (xs >= 0.f) ? x2[r] * mx : x2[r] * mn;  // exact max of x2*kv
    }

    f32x4 acc[2][8];
    #pragma unroll
    for (int r = 0; r < 2; ++r)
        #pragma unroll
        for (int e = 0; e < 8; ++e) acc[r][e] = (f32x4){0.f, 0.f, 0.f, 0.f};

    float den[2] = {0.f, 0.f};
    int sgrp = (lane >> 4) << 3;  // 0,8,16,24 : this lane-group's k offset
    const float* kvp = Kpad + h * S_PAD;
    const __hip_bfloat16* vbase = Vt + (size_t)(h * DK + (lane & 15)) * S_PAD;

    for (int s0 = 0; s0 < S_PAD; s0 += 32) {
        int sb = s0 + sgrp;
        float4 kA = *(const float4*)(kvp + sb);
        float4 kB = *(const float4*)(kvp + sb + 4);
        float kv[8] = {kA.x, kA.y, kA.z, kA.w, kB.x, kB.y, kB.z, kB.w};
        short8 afr[2];
        #pragma unroll
        for (int r = 0; r < 2; ++r) {
            #pragma unroll
            for (int j = 0; j < 8; ++j) {
                float w = exp2f(fmaf(x2[r], kv[j], -mref2[r]));
                w = (sb + j < S_LEN) ? w : 0.f;
                den[r] += w;
                __hip_bfloat16 hb = __float2bfloat16(w);
                afr[r][j] = __builtin_bit_cast(short, hb);
            }
        }
        const __hip_bfloat16* vp = vbase + sb;
        #pragma unroll
        for (int e = 0; e < 8; ++e) {
            short8 bf = *(const short8*)(vp + (size_t)e * 16 * S_PAD);
            acc[0][e] = __builtin_amdgcn_mfma_f32_16x16x32_bf16(afr[0], bf, acc[0][e], 0, 0, 0);
            acc[1][e] = __builtin_amdgcn_mfma_f32_16x16x32_bf16(afr[1], bf, acc[1][e], 0, 0, 0);
        }
    }

    #pragma unroll
    for (int r = 0; r < 2; ++r) {
        den[r] += __shfl_xor(den[r], 16);
        den[r] += __shfl_xor(den[r], 32);
    }
    int rowoff = (lane >> 4) << 2;
    #pragma unroll
    for (int r = 0; r < 2; ++r) {
        float inv[4];
        #pragma unroll
        for (int q = 0; q < 4; ++q) inv[q] = 1.0f / __shfl(den[r], rowoff + q);
        #pragma unroll
        for (int e = 0; e < 8; ++e) {
            #pragma unroll
            for (int q = 0; q < 4; ++q) {
                int mrow = m0 + r * 16 + rowoff + q;
                attB[(size_t)mrow * DKH + h * DK + e * 16 + (lane & 15)] =
                    __float2bfloat16(acc[r][e][q] * inv[q]);
            }
        }
    }
}

// ---------------- out projection via MFMA: C[12288][768] = A_bf16 @ Wot^T + bo ----------------
__global__ __launch_bounds__(256) void outproj_mfma_kernel(const __hip_bfloat16* __restrict__ A,
                                                           const __hip_bfloat16* __restrict__ Bt,
                                                           const float* __restrict__ bo,
                                                           float* __restrict__ C) {
    int lane = threadIdx.x & 63;
    int w = threadIdx.x >> 6;
    int wy = w >> 1, wx = w & 1;
    int m0 = blockIdx.y * 64 + wy * 32;
    int n0 = blockIdx.x * 128 + wx * 64;
    int sgrp = (lane >> 4) << 3;

    f32x4 acc[2][4];
    #pragma unroll
    for (int r = 0; r < 2; ++r)
        #pragma unroll
        for (int c = 0; c < 4; ++c) acc[r][c] = (f32x4){0.f, 0.f, 0.f, 0.f};

    const __hip_bfloat16* ap = A + (size_t)(m0 + (lane & 15)) * DKH + sgrp;
    const __hip_bfloat16* bp = Bt + (size_t)(n0 + (lane & 15)) * DKH + sgrp;

    for (int k0 = 0; k0 < DKH; k0 += 32) {
        short8 af[2], bf[4];
        af[0] = *(const short8*)(ap + k0);
        af[1] = *(const short8*)(ap + 16 * DKH + k0);
        #pragma unroll
        for (int c = 0; c < 4; ++c) bf[c] = *(const short8*)(bp + (size_t)c * 16 * DKH + k0);
        #pragma unroll
        for (int r = 0; r < 2; ++r)
            #pragma unroll
            for (int c = 0; c < 4; ++c)
                acc[r][c] = __builtin_amdgcn_mfma_f32_16x16x32_bf16(af[r], bf[c], acc[r][c], 0, 0, 0);
    }

    int rowoff = (lane >> 4) << 2;
    #pragma unroll
    for (int r = 0; r < 2; ++r) {
        #pragma unroll
        for (int c = 0; c < 4; ++c) {
            int col = n0 + c * 16 + (lane & 15);
            float b = bo[col];
            #pragma unroll
            for (int q = 0; q < 4; ++q) {
                int row = m0 + r * 16 + rowoff + q;
                C[(size_t)row * D_LLM + col] = acc[r][c][q] + b;
            }
        }
    }
}

extern "C" void kernel_launch(void* const* d_in, const int* in_sizes, int n_in,
                              void* d_out, int out_size, void* d_ws, size_t ws_size,
                              hipStream_t stream) {
    const float* ts   = (const float*)d_in[0];
    const float* src  = (const float*)d_in[1];
    const float* vemb = (const float*)d_in[2];
    const float* Wk   = (const float*)d_in[3];
    const float* bk   = (const float*)d_in[4];
    const float* Wv   = (const float*)d_in[5];
    const float* bv   = (const float*)d_in[6];
    const float* Wo   = (const float*)d_in[7];
    const float* bo   = (const float*)d_in[8];
    float* out = (float*)d_out;

    // workspace layout (float offsets; all 16B aligned)
    float* ws = (float*)d_ws;
    float* V      = ws;                          // 1000*1024        = 1,024,000 f
    float* Kpad   = ws + 1024000;                // 8*1024           = 8,192 f
    float* Wksum  = ws + 1032192;                // 768*8            = 6,144 f
    float* bksum  = ws + 1038336;                // 8 f
    float* mnmx   = ws + 1038344;                // 16 f
    __hip_bfloat16* Vt   = (__hip_bfloat16*)(ws + 1040000);  // 1024*1024 bf16 = 524,288 f
    __hip_bfloat16* Wot  = (__hip_bfloat16*)(ws + 1600000);  // 768*1024 bf16  = 393,216 f
    __hip_bfloat16* attB = (__hip_bfloat16*)(ws + 2000000);  // 12288*1024 bf16 = 6,291,456 f

    // 1) Wksum / bksum
    wksum_kernel<<<(D_LLM * NH + 255) / 256, 256, 0, stream>>>(Wk, bk, Wksum, bksum);
    // 2) Kpad (zero-padded to 1024)
    ksum_kernel<<<(S_PAD * NH) / 4, 256, 0, stream>>>(src, Wksum, bksum, Kpad);
    // 3) min/max per head
    kminmax_kernel<<<1, 512, 0, stream>>>(Kpad, mnmx);
    // 4) V projection: [1000,768] @ [768,1024] + bv  (fp32)
    {
        dim3 grid(DKH / BN, (S_LEN + BM - 1) / BM);
        gemm_bias_kernel<<<grid, 256, 0, stream>>>(vemb, Wv, bv, V, S_LEN, DKH, D_LLM);
    }
    // 5) transposes to bf16
    {
        dim3 gv(S_PAD / 32, DKH / 32);
        vtrans_kernel<<<gv, 256, 0, stream>>>(V, Vt);
        dim3 gw(DKH / 32, D_LLM / 32);
        wtrans_kernel<<<gw, 256, 0, stream>>>(Wo, Wot);
    }
    // 6) fused softmax + PV (MFMA), writes attB bf16
    attn_mfma_kernel<<<768, 256, 0, stream>>>(ts, Kpad, mnmx, Vt, attB);
    // 7) out projection (MFMA): [12288,1024] @ [1024,768] + bo
    {
        dim3 grid(D_LLM / 128, M_ROWS / 64);
        outproj_mfma_kernel<<<grid, 256, 0, stream>>>(attB, Wot, bo, out);
    }
}

// Round 3
// 227.058 us; speedup vs baseline: 5.6462x; 1.3502x over previous
//
#include <hip/hip_runtime.h>
#include <hip/hip_bf16.h>
#include <math.h>

#define D_LLM 768
#define DKH   1024   // d_keys * n_heads = 128*8
#define NH    8
#define DK    128
#define S_LEN 1000
#define S_PAD 1024
#define M_ROWS 12288 // B*N*T = 128*96
#define T_LEN 96
#define N_VARS 16

typedef __attribute__((ext_vector_type(8))) short short8;
typedef __attribute__((ext_vector_type(4))) float f32x4;

__device__ __forceinline__ void gload_lds16(const void* g, void* l) {
    __builtin_amdgcn_global_load_lds(
        (const __attribute__((address_space(1))) unsigned int*)g,
        (__attribute__((address_space(3))) unsigned int*)l, 16, 0, 0);
}

// ---------------- Wksum: Wksum[d][h] = sum_e Wk[d][h*128+e]; bksum[h] = sum_e bk ----------------
__global__ void wksum_kernel(const float* __restrict__ Wk, const float* __restrict__ bk,
                             float* __restrict__ Wksum, float* __restrict__ bksum) {
    int idx = blockIdx.x * 256 + threadIdx.x;
    if (idx < D_LLM * NH) {
        int d = idx / NH, h = idx % NH;
        float acc = 0.f;
        const float* p = Wk + (size_t)d * DKH + h * DK;
        #pragma unroll 8
        for (int e = 0; e < DK; ++e) acc += p[e];
        Wksum[d * NH + h] = acc;
    }
    if (idx < NH) {
        float acc = 0.f;
        const float* p = bk + idx * DK;
        for (int e = 0; e < DK; ++e) acc += p[e];
        bksum[idx] = acc;
    }
}

// ---------------- Kpad[h][s] = src[s,:] . Wksum[:,h] + bksum[h]  (s>=1000 -> 0) ----------------
__global__ __launch_bounds__(256) void ksum_kernel(const float* __restrict__ src,
                                                   const float* __restrict__ Wksum,
                                                   const float* __restrict__ bksum,
                                                   float* __restrict__ Kpad) {
    int wave = blockIdx.x * 4 + (threadIdx.x >> 6);
    int lane = threadIdx.x & 63;
    if (wave >= S_PAD * NH) return;
    int s = wave >> 3, h = wave & 7;
    if (s >= S_LEN) { if (lane == 0) Kpad[h * S_PAD + s] = 0.f; return; }
    float acc = 0.f;
    const float* sp = src + (size_t)s * D_LLM;
    for (int d = lane; d < D_LLM; d += 64) acc += sp[d] * Wksum[d * NH + h];
    #pragma unroll
    for (int off = 32; off > 0; off >>= 1) acc += __shfl_down(acc, off);
    if (lane == 0) Kpad[h * S_PAD + s] = acc + bksum[h];
}

// ---------------- per-head min/max of Kpad over s<1000 ----------------
__global__ __launch_bounds__(512) void kminmax_kernel(const float* __restrict__ Kpad,
                                                      float* __restrict__ mnmx) {
    int h = threadIdx.x >> 6, lane = threadIdx.x & 63;
    float mx = -1e30f, mn = 1e30f;
    for (int s = lane; s < S_LEN; s += 64) {
        float v = Kpad[h * S_PAD + s];
        mx = fmaxf(mx, v); mn = fminf(mn, v);
    }
    #pragma unroll
    for (int off = 32; off > 0; off >>= 1) {
        mx = fmaxf(mx, __shfl_down(mx, off));
        mn = fminf(mn, __shfl_down(mn, off));
    }
    if (lane == 0) { mnmx[h * 2] = mn; mnmx[h * 2 + 1] = mx; }
}

// ---------------- V projection + fused transpose: Vt[c][s] = bf16(vemb[s,:]@Wv[:,c] + bv[c]) ----------------
#define BM 64
#define BN 64
#define BK 16
__global__ __launch_bounds__(256) void vproj_trans_kernel(const float* __restrict__ A,
                                                          const float* __restrict__ B,
                                                          const float* __restrict__ bias,
                                                          __hip_bfloat16* __restrict__ Vt) {
    __shared__ float As[BK][BM + 1];
    __shared__ float Bs[BK][BN + 1];
    int tid = threadIdx.x;
    int tx = tid & 15, ty = tid >> 4;
    int row0 = blockIdx.y * BM + ty * 4;
    int col0 = blockIdx.x * BN + tx * 4;
    float acc[4][4] = {};
    int fA = tid * 4;
    int a_m = fA >> 4;
    int a_k = fA & 15;
    int b_k = fA >> 6;
    int b_n = fA & 63;
    int a_row = blockIdx.y * BM + a_m;
    const float* Bcol = B + blockIdx.x * BN + b_n;
    for (int k0 = 0; k0 < D_LLM; k0 += BK) {
        float4 av = make_float4(0.f, 0.f, 0.f, 0.f);
        if (a_row < S_LEN) av = *(const float4*)(A + (size_t)a_row * D_LLM + k0 + a_k);
        As[a_k + 0][a_m] = av.x; As[a_k + 1][a_m] = av.y;
        As[a_k + 2][a_m] = av.z; As[a_k + 3][a_m] = av.w;
        float4 bv = *(const float4*)(Bcol + (size_t)(k0 + b_k) * DKH);
        Bs[b_k][b_n + 0] = bv.x; Bs[b_k][b_n + 1] = bv.y;
        Bs[b_k][b_n + 2] = bv.z; Bs[b_k][b_n + 3] = bv.w;
        __syncthreads();
        #pragma unroll
        for (int kk = 0; kk < BK; ++kk) {
            float a0 = As[kk][ty * 4 + 0], a1 = As[kk][ty * 4 + 1];
            float a2 = As[kk][ty * 4 + 2], a3 = As[kk][ty * 4 + 3];
            float b0 = Bs[kk][tx * 4 + 0], b1 = Bs[kk][tx * 4 + 1];
            float b2 = Bs[kk][tx * 4 + 2], b3 = Bs[kk][tx * 4 + 3];
            acc[0][0] += a0 * b0; acc[0][1] += a0 * b1; acc[0][2] += a0 * b2; acc[0][3] += a0 * b3;
            acc[1][0] += a1 * b0; acc[1][1] += a1 * b1; acc[1][2] += a1 * b2; acc[1][3] += a1 * b3;
            acc[2][0] += a2 * b0; acc[2][1] += a2 * b1; acc[2][2] += a2 * b2; acc[2][3] += a2 * b3;
            acc[3][0] += a3 * b0; acc[3][1] += a3 * b1; acc[3][2] += a3 * b2; acc[3][3] += a3 * b3;
        }
        __syncthreads();
    }
    #pragma unroll
    for (int i = 0; i < 4; ++i) {
        int r = row0 + i;
        #pragma unroll
        for (int j = 0; j < 4; ++j) {
            int c = col0 + j;
            float v = (r < S_LEN) ? (acc[i][j] + bias[c]) : 0.f;
            Vt[(size_t)c * S_PAD + r] = __float2bfloat16(v);
        }
    }
}

// ---------------- transpose Wo fp32[1024][768] -> Wot bf16[768][1024] ----------------
__global__ __launch_bounds__(256) void wtrans_kernel(const float* __restrict__ Wo,
                                                     __hip_bfloat16* __restrict__ Wot) {
    __shared__ float t[32][33];
    int tx = threadIdx.x & 31, ty = threadIdx.x >> 5;
    int k0 = blockIdx.x * 32, n0 = blockIdx.y * 32;
    #pragma unroll
    for (int p = 0; p < 4; ++p) {
        int k = k0 + ty + p * 8;
        t[ty + p * 8][tx] = Wo[(size_t)k * D_LLM + n0 + tx];
    }
    __syncthreads();
    #pragma unroll
    for (int p = 0; p < 4; ++p) {
        int n = n0 + ty + p * 8;
        Wot[(size_t)n * DKH + k0 + tx] = __float2bfloat16(t[tx][ty + p * 8]);
    }
}

// ---------------- fused softmax + PV via MFMA ----------------
// block: 4 waves, ONE head (blockIdx.y), wave = 32 consecutive rows; K-loop over s (step 32)
__global__ __launch_bounds__(256) void attn_mfma_kernel(const float* __restrict__ ts,
                                                        const float* __restrict__ Kpad,
                                                        const float* __restrict__ mnmx,
                                                        const __hip_bfloat16* __restrict__ Vt,
                                                        __hip_bfloat16* __restrict__ attB) {
    int lane = threadIdx.x & 63;
    int h = blockIdx.y;
    int p = blockIdx.x * 4 + (threadIdx.x >> 6);
    int m0 = p * 32;

    float mn = mnmx[h * 2], mx = mnmx[h * 2 + 1];
    float x2[2], mref2[2];
    #pragma unroll
    for (int r = 0; r < 2; ++r) {
        int m = m0 + r * 16 + (lane & 15);
        int t = m % T_LEN;
        int rr = m / T_LEN;
        int b = rr >> 4, n = rr & 15;
        float v = ts[((size_t)b * T_LEN + t) * N_VARS + n];
        if (v != v) v = 0.f;
        float xs = v * 0.08838834764831845f;  // 1/sqrt(128)
        x2[r] = xs * 1.44269504088896f;       // /ln2 for exp2
        mref2[r] = (xs >= 0.f) ? x2[r] * mx : x2[r] * mn;  // exact max of x2*kv over s<1000
    }

    f32x4 acc[2][8];
    #pragma unroll
    for (int r = 0; r < 2; ++r)
        #pragma unroll
        for (int e = 0; e < 8; ++e) acc[r][e] = (f32x4){0.f, 0.f, 0.f, 0.f};

    float den[2] = {0.f, 0.f};
    int sgrp = (lane >> 4) << 3;
    const float* kvp = Kpad + h * S_PAD;
    const __hip_bfloat16* vbase = Vt + (size_t)(h * DK + (lane & 15)) * S_PAD;

    for (int s0 = 0; s0 < S_PAD; s0 += 32) {
        int sb = s0 + sgrp;
        float4 kA = *(const float4*)(kvp + sb);
        float4 kB = *(const float4*)(kvp + sb + 4);
        float kv[8] = {kA.x, kA.y, kA.z, kA.w, kB.x, kB.y, kB.z, kB.w};
        short8 afr[2];
        #pragma unroll
        for (int r = 0; r < 2; ++r) {
            #pragma unroll
            for (int j = 0; j < 8; ++j) {
                // padded s have kv==0 -> w = exp2(-mref2[r]); corrected in den afterwards,
                // and Vt is zero there so PV is unaffected.
                float w = __builtin_amdgcn_exp2f(fmaf(x2[r], kv[j], -mref2[r]));
                den[r] += w;
                __hip_bfloat16 hb = __float2bfloat16(w);
                afr[r][j] = __builtin_bit_cast(short, hb);
            }
        }
        const __hip_bfloat16* vp = vbase + sb;
        #pragma unroll
        for (int e = 0; e < 8; ++e) {
            short8 bf = *(const short8*)(vp + (size_t)e * 16 * S_PAD);
            acc[0][e] = __builtin_amdgcn_mfma_f32_16x16x32_bf16(afr[0], bf, acc[0][e], 0, 0, 0);
            acc[1][e] = __builtin_amdgcn_mfma_f32_16x16x32_bf16(afr[1], bf, acc[1][e], 0, 0, 0);
        }
    }

    #pragma unroll
    for (int r = 0; r < 2; ++r) {
        den[r] += __shfl_xor(den[r], 16);
        den[r] += __shfl_xor(den[r], 32);
        den[r] -= 24.f * __builtin_amdgcn_exp2f(-mref2[r]);  // exact pad correction (24 pads)
    }
    int rowoff = (lane >> 4) << 2;
    #pragma unroll
    for (int r = 0; r < 2; ++r) {
        float inv[4];
        #pragma unroll
        for (int q = 0; q < 4; ++q) inv[q] = 1.0f / __shfl(den[r], rowoff + q);
        #pragma unroll
        for (int e = 0; e < 8; ++e) {
            #pragma unroll
            for (int q = 0; q < 4; ++q) {
                int mrow = m0 + r * 16 + rowoff + q;
                attB[(size_t)mrow * DKH + h * DK + e * 16 + (lane & 15)] =
                    __float2bfloat16(acc[r][e][q] * inv[q]);
            }
        }
    }
}

// ---------------- out projection via MFMA, m97-style LDS staging ----------------
// 128x128 tile, BK=32, 4 waves each 64x64; C[12288][768] = A_bf16[12288][1024] @ Wot^T + bo
__global__ __launch_bounds__(256) void outproj_mfma_kernel(const __hip_bfloat16* __restrict__ A,
                                                           const __hip_bfloat16* __restrict__ Bt,
                                                           const float* __restrict__ bo,
                                                           float* __restrict__ C) {
    __shared__ __hip_bfloat16 As[128 * 32];
    __shared__ __hip_bfloat16 Bs[128 * 32];
    int t = threadIdx.x;
    int w = t >> 6, lane = t & 63;
    int wr = w >> 1, wc = w & 1;
    int bm0 = blockIdx.y * 128;
    int bn0 = blockIdx.x * 128;

    // staging coords: thread t covers row t/4 (+64 for issue 1), k-col (t%4)*8
    int lrow = t >> 2;
    int lcol = (t & 3) * 8;
    const __hip_bfloat16* ga0 = A + (size_t)(bm0 + lrow) * DKH + lcol;
    const __hip_bfloat16* ga1 = A + (size_t)(bm0 + 64 + lrow) * DKH + lcol;
    const __hip_bfloat16* gb0 = Bt + (size_t)(bn0 + lrow) * DKH + lcol;
    const __hip_bfloat16* gb1 = Bt + (size_t)(bn0 + 64 + lrow) * DKH + lcol;
    char* lA = (char*)As + w * 1024;  // wave-uniform base; HW adds lane*16
    char* lB = (char*)Bs + w * 1024;

    f32x4 acc[4][4];
    #pragma unroll
    for (int m = 0; m < 4; ++m)
        #pragma unroll
        for (int n = 0; n < 4; ++n) acc[m][n] = (f32x4){0.f, 0.f, 0.f, 0.f};

    int sgrp = (lane >> 4) << 3;
    int arow = wr * 64 + (lane & 15);
    int brow = wc * 64 + (lane & 15);

    for (int k0 = 0; k0 < DKH; k0 += 32) {
        gload_lds16(ga0 + k0, lA);
        gload_lds16(ga1 + k0, lA + 4096);
        gload_lds16(gb0 + k0, lB);
        gload_lds16(gb1 + k0, lB + 4096);
        __syncthreads();
        short8 af[4], bf[4];
        #pragma unroll
        for (int m = 0; m < 4; ++m)
            af[m] = *(const short8*)(As + (size_t)(arow + m * 16) * 32 + sgrp);
        #pragma unroll
        for (int n = 0; n < 4; ++n)
            bf[n] = *(const short8*)(Bs + (size_t)(brow + n * 16) * 32 + sgrp);
        #pragma unroll
        for (int m = 0; m < 4; ++m)
            #pragma unroll
            for (int n = 0; n < 4; ++n)
                acc[m][n] = __builtin_amdgcn_mfma_f32_16x16x32_bf16(af[m], bf[n], acc[m][n], 0, 0, 0);
        __syncthreads();
    }

    int rowoff = (lane >> 4) << 2;
    #pragma unroll
    for (int m = 0; m < 4; ++m) {
        #pragma unroll
        for (int n = 0; n < 4; ++n) {
            int col = bn0 + wc * 64 + n * 16 + (lane & 15);
            float b = bo[col];
            #pragma unroll
            for (int q = 0; q < 4; ++q) {
                int row = bm0 + wr * 64 + m * 16 + rowoff + q;
                C[(size_t)row * D_LLM + col] = acc[m][n][q] + b;
            }
        }
    }
}

extern "C" void kernel_launch(void* const* d_in, const int* in_sizes, int n_in,
                              void* d_out, int out_size, void* d_ws, size_t ws_size,
                              hipStream_t stream) {
    const float* ts   = (const float*)d_in[0];
    const float* src  = (const float*)d_in[1];
    const float* vemb = (const float*)d_in[2];
    const float* Wk   = (const float*)d_in[3];
    const float* bk   = (const float*)d_in[4];
    const float* Wv   = (const float*)d_in[5];
    const float* bv   = (const float*)d_in[6];
    const float* Wo   = (const float*)d_in[7];
    const float* bo   = (const float*)d_in[8];
    float* out = (float*)d_out;

    // workspace layout (float offsets; all 16B aligned)
    float* ws = (float*)d_ws;
    float* Kpad   = ws;                        // 8,192 f
    float* Wksum  = ws + 8192;                 // 6,144 f
    float* bksum  = ws + 14336;                // 8 f
    float* mnmx   = ws + 14344;                // 16 f
    __hip_bfloat16* Vt   = (__hip_bfloat16*)(ws + 14592);    // 1024*1024 bf16 = 524,288 f
    __hip_bfloat16* Wot  = (__hip_bfloat16*)(ws + 540000);   // 768*1024 bf16  = 393,216 f
    __hip_bfloat16* attB = (__hip_bfloat16*)(ws + 940000);   // 12288*1024 bf16 = 6,291,456 f

    // 1) Wksum / bksum
    wksum_kernel<<<(D_LLM * NH + 255) / 256, 256, 0, stream>>>(Wk, bk, Wksum, bksum);
    // 2) Kpad (zero-padded to 1024)
    ksum_kernel<<<(S_PAD * NH) / 4, 256, 0, stream>>>(src, Wksum, bksum, Kpad);
    // 3) min/max per head
    kminmax_kernel<<<1, 512, 0, stream>>>(Kpad, mnmx);
    // 4) V projection fused with transpose -> Vt bf16 [1024][1024] (zero-padded)
    {
        dim3 grid(DKH / BN, S_PAD / BM);
        vproj_trans_kernel<<<grid, 256, 0, stream>>>(vemb, Wv, bv, Vt);
    }
    // 5) Wo transpose -> bf16
    {
        dim3 gw(DKH / 32, D_LLM / 32);
        wtrans_kernel<<<gw, 256, 0, stream>>>(Wo, Wot);
    }
    // 6) fused softmax + PV (MFMA), writes attB bf16
    {
        dim3 grid(96, NH);
        attn_mfma_kernel<<<grid, 256, 0, stream>>>(ts, Kpad, mnmx, Vt, attB);
    }
    // 7) out projection (MFMA, LDS-staged): [12288,1024] @ [1024,768] + bo
    {
        dim3 grid(D_LLM / 128, M_ROWS / 128);
        outproj_mfma_kernel<<<grid, 256, 0, stream>>>(attB, Wot, bo, out);
    }
}

// Round 4
// 126.006 us; speedup vs baseline: 10.1743x; 1.8020x over previous
//
#include <hip/hip_runtime.h>
#include <hip/hip_bf16.h>
#include <math.h>

#define D_LLM 768
#define DKH   1024   // d_keys * n_heads = 128*8
#define NH    8
#define DK    128
#define S_LEN 1000
#define S_PAD 1024
#define M_ROWS 12288 // B*N*T = 128*96
#define T_LEN 96
#define N_VARS 16

static constexpr float SCALE_EXP2 = (float)(0.08838834764831845 * 1.4426950408889634); // 1/sqrt(128)/ln2

typedef __attribute__((ext_vector_type(8))) short short8;
typedef __attribute__((ext_vector_type(4))) float f32x4;

__device__ __forceinline__ void gload_lds16(const void* g, void* l) {
    __builtin_amdgcn_global_load_lds(
        (const __attribute__((address_space(1))) unsigned int*)g,
        (__attribute__((address_space(3))) unsigned int*)l, 16, 0, 0);
}

// ---------------- Wksum[d][h] = sum_e Wk[d][h*128+e]; bksum[h] = sum_e bk ----------------
// wave per d-row (coalesced float4), last block does bias.
__global__ __launch_bounds__(256) void wksum_kernel(const float* __restrict__ Wk,
                                                    const float* __restrict__ bk,
                                                    float* __restrict__ Wksum,
                                                    float* __restrict__ bksum) {
    int w = threadIdx.x >> 6, lane = threadIdx.x & 63;
    int blk = blockIdx.x;
    if (blk < 192) {
        int d = blk * 4 + w;
        const float* p = Wk + (size_t)d * DKH + lane * 16;
        float s = 0.f;
        #pragma unroll
        for (int i = 0; i < 4; ++i) {
            float4 v = *(const float4*)(p + i * 4);
            s += v.x + v.y + v.z + v.w;
        }
        s += __shfl_down(s, 4);
        s += __shfl_down(s, 2);
        s += __shfl_down(s, 1);
        if ((lane & 7) == 0) Wksum[d * NH + (lane >> 3)] = s;
    } else if (w == 0) {
        const float* p = bk + lane * 16;
        float s = 0.f;
        #pragma unroll
        for (int i = 0; i < 4; ++i) {
            float4 v = *(const float4*)(p + i * 4);
            s += v.x + v.y + v.z + v.w;
        }
        s += __shfl_down(s, 4);
        s += __shfl_down(s, 2);
        s += __shfl_down(s, 1);
        if ((lane & 7) == 0) bksum[lane >> 3] = s;
    }
}

// ---------------- Kpad[h][s] = (src[s,:].Wksum[:,h] + bksum[h]) * SCALE_EXP2 (s>=1000 -> 0) ----------------
// wave per s: src row read ONCE for all 8 heads.
__global__ __launch_bounds__(256) void ksum_kernel(const float* __restrict__ src,
                                                   const float* __restrict__ Wksum,
                                                   const float* __restrict__ bksum,
                                                   float* __restrict__ Kpad) {
    int w = threadIdx.x >> 6, lane = threadIdx.x & 63;
    int s = blockIdx.x * 4 + w;
    if (s >= S_LEN) {
        if (lane < 8) Kpad[lane * S_PAD + s] = 0.f;
        return;
    }
    const float* sp = src + (size_t)s * D_LLM + lane * 12;
    float xv[12];
    ((float4*)xv)[0] = *(const float4*)(sp);
    ((float4*)xv)[1] = *(const float4*)(sp + 4);
    ((float4*)xv)[2] = *(const float4*)(sp + 8);
    float a[8] = {0.f, 0.f, 0.f, 0.f, 0.f, 0.f, 0.f, 0.f};
    const float* wp = Wksum + lane * 12 * NH;
    #pragma unroll
    for (int i = 0; i < 12; ++i) {
        float4 wa = *(const float4*)(wp + i * 8);
        float4 wb = *(const float4*)(wp + i * 8 + 4);
        a[0] = fmaf(xv[i], wa.x, a[0]); a[1] = fmaf(xv[i], wa.y, a[1]);
        a[2] = fmaf(xv[i], wa.z, a[2]); a[3] = fmaf(xv[i], wa.w, a[3]);
        a[4] = fmaf(xv[i], wb.x, a[4]); a[5] = fmaf(xv[i], wb.y, a[5]);
        a[6] = fmaf(xv[i], wb.z, a[6]); a[7] = fmaf(xv[i], wb.w, a[7]);
    }
    #pragma unroll
    for (int off = 32; off > 0; off >>= 1) {
        #pragma unroll
        for (int hh = 0; hh < 8; ++hh) a[hh] += __shfl_xor(a[hh], off);
    }
    #pragma unroll
    for (int hh = 0; hh < 8; ++hh)
        if (lane == hh) Kpad[hh * S_PAD + s] = (a[hh] + bksum[hh]) * SCALE_EXP2;
}

// ---------------- per-head min/max of Kpad over s<1000 (scaled units) ----------------
__global__ __launch_bounds__(64) void kminmax_kernel(const float* __restrict__ Kpad,
                                                     float* __restrict__ mnmx) {
    int h = blockIdx.x, lane = threadIdx.x;
    float mx = -1e30f, mn = 1e30f;
    for (int s = lane; s < S_LEN; s += 64) {
        float v = Kpad[h * S_PAD + s];
        mx = fmaxf(mx, v); mn = fminf(mn, v);
    }
    #pragma unroll
    for (int off = 32; off > 0; off >>= 1) {
        mx = fmaxf(mx, __shfl_xor(mx, off));
        mn = fminf(mn, __shfl_xor(mn, off));
    }
    if (lane == 0) { mnmx[h * 2] = mn; mnmx[h * 2 + 1] = mx; }
}

// ---------------- vemb fp32 -> bf16, rows >= 1000 zero-padded ----------------
__global__ __launch_bounds__(192) void acvt_kernel(const float* __restrict__ A,
                                                   __hip_bfloat16* __restrict__ Ab) {
    int row = blockIdx.x, c4 = threadIdx.x;
    float4 v = make_float4(0.f, 0.f, 0.f, 0.f);
    if (row < S_LEN) v = *(const float4*)(A + (size_t)row * D_LLM + c4 * 4);
    short4 o;
    o.x = __builtin_bit_cast(short, __float2bfloat16(v.x));
    o.y = __builtin_bit_cast(short, __float2bfloat16(v.y));
    o.z = __builtin_bit_cast(short, __float2bfloat16(v.z));
    o.w = __builtin_bit_cast(short, __float2bfloat16(v.w));
    *(short4*)(Ab + (size_t)row * D_LLM + c4 * 4) = o;
}

// ---------------- transpose Wv fp32[768][1024] -> Wvt bf16[1024][768] ----------------
__global__ __launch_bounds__(256) void wvtrans_kernel(const float* __restrict__ Wv,
                                                      __hip_bfloat16* __restrict__ Wvt) {
    __shared__ float t[32][33];
    int tx = threadIdx.x & 31, ty = threadIdx.x >> 5;
    int k0 = blockIdx.x * 32, n0 = blockIdx.y * 32;
    #pragma unroll
    for (int p = 0; p < 4; ++p) {
        int k = k0 + ty + p * 8;
        t[ty + p * 8][tx] = Wv[(size_t)k * DKH + n0 + tx];
    }
    __syncthreads();
    #pragma unroll
    for (int p = 0; p < 4; ++p) {
        int n = n0 + ty + p * 8;
        Wvt[(size_t)n * D_LLM + k0 + tx] = __float2bfloat16(t[tx][ty + p * 8]);
    }
}

// ---------------- transpose Wo fp32[1024][768] -> Wot bf16[768][1024] ----------------
__global__ __launch_bounds__(256) void wtrans_kernel(const float* __restrict__ Wo,
                                                     __hip_bfloat16* __restrict__ Wot) {
    __shared__ float t[32][33];
    int tx = threadIdx.x & 31, ty = threadIdx.x >> 5;
    int k0 = blockIdx.x * 32, n0 = blockIdx.y * 32;
    #pragma unroll
    for (int p = 0; p < 4; ++p) {
        int k = k0 + ty + p * 8;
        t[ty + p * 8][tx] = Wo[(size_t)k * D_LLM + n0 + tx];
    }
    __syncthreads();
    #pragma unroll
    for (int p = 0; p < 4; ++p) {
        int n = n0 + ty + p * 8;
        Wot[(size_t)n * DKH + k0 + tx] = __float2bfloat16(t[tx][ty + p * 8]);
    }
}

// ---------------- V projection via MFMA: Vt[c][s^swz] = bf16(vemb@Wv + bv) ----------------
// M=1024(s) N=1024(c) K=768. 128x128 tile, LDS-staged, epilogue writes swizzled transpose.
__global__ __launch_bounds__(256) void vproj_mfma_kernel(const __hip_bfloat16* __restrict__ A,
                                                         const __hip_bfloat16* __restrict__ Bt,
                                                         const float* __restrict__ bias,
                                                         __hip_bfloat16* __restrict__ Vt) {
    __shared__ __hip_bfloat16 As[128 * 32];
    __shared__ __hip_bfloat16 Bs[128 * 32];
    int t = threadIdx.x;
    int w = t >> 6, lane = t & 63;
    int wr = w >> 1, wc = w & 1;
    int bm0 = blockIdx.y * 128, bn0 = blockIdx.x * 128;
    int lrow = t >> 2, lcol = (t & 3) * 8;
    const __hip_bfloat16* ga0 = A + (size_t)(bm0 + lrow) * D_LLM + lcol;
    const __hip_bfloat16* ga1 = A + (size_t)(bm0 + 64 + lrow) * D_LLM + lcol;
    const __hip_bfloat16* gb0 = Bt + (size_t)(bn0 + lrow) * D_LLM + lcol;
    const __hip_bfloat16* gb1 = Bt + (size_t)(bn0 + 64 + lrow) * D_LLM + lcol;
    char* lA = (char*)As + w * 1024;
    char* lB = (char*)Bs + w * 1024;

    f32x4 acc[4][4];
    #pragma unroll
    for (int m = 0; m < 4; ++m)
        #pragma unroll
        for (int n = 0; n < 4; ++n) acc[m][n] = (f32x4){0.f, 0.f, 0.f, 0.f};

    int sgrp = (lane >> 4) << 3;
    int arow = wr * 64 + (lane & 15);
    int brow = wc * 64 + (lane & 15);

    for (int k0 = 0; k0 < D_LLM; k0 += 32) {
        gload_lds16(ga0 + k0, lA);
        gload_lds16(ga1 + k0, lA + 4096);
        gload_lds16(gb0 + k0, lB);
        gload_lds16(gb1 + k0, lB + 4096);
        __syncthreads();
        short8 af[4], bf[4];
        #pragma unroll
        for (int m = 0; m < 4; ++m)
            af[m] = *(const short8*)(As + (size_t)(arow + m * 16) * 32 + sgrp);
        #pragma unroll
        for (int n = 0; n < 4; ++n)
            bf[n] = *(const short8*)(Bs + (size_t)(brow + n * 16) * 32 + sgrp);
        #pragma unroll
        for (int m = 0; m < 4; ++m)
            #pragma unroll
            for (int n = 0; n < 4; ++n)
                acc[m][n] = __builtin_amdgcn_mfma_f32_16x16x32_bf16(af[m], bf[n], acc[m][n], 0, 0, 0);
        __syncthreads();
    }

    int rowoff = (lane >> 4) << 2;
    #pragma unroll
    for (int m = 0; m < 4; ++m) {
        #pragma unroll
        for (int n = 0; n < 4; ++n) {
            int c = bn0 + wc * 64 + n * 16 + (lane & 15);
            float b = bias[c];
            int csw = ((c ^ (c >> 2)) & 3) << 3;
            #pragma unroll
            for (int q = 0; q < 4; ++q) {
                int srow = bm0 + wr * 64 + m * 16 + rowoff + q;
                float val = (srow < S_LEN) ? acc[m][n][q] + b : 0.f;
                Vt[(size_t)c * S_PAD + (srow ^ csw)] = __float2bfloat16(val);
            }
        }
    }
}

// ---------------- fused softmax + PV via MFMA, LDS-staged V, den via ones-MFMA ----------------
__global__ __launch_bounds__(256) void attn_mfma_kernel(const float* __restrict__ ts,
                                                        const float* __restrict__ Kpad,
                                                        const float* __restrict__ mnmx,
                                                        const __hip_bfloat16* __restrict__ Vt,
                                                        __hip_bfloat16* __restrict__ attB) {
    __shared__ __hip_bfloat16 Vs[2][4096];   // 2 x 8KB double buffer: [e 0..127][s-chunk swizzled]
    int tid = threadIdx.x;
    int lane = tid & 63;
    int w = tid >> 6;
    int h = blockIdx.y;
    int m0 = (blockIdx.x * 4 + w) * 32;
    int l15 = lane & 15;
    int q = lane >> 4;
    int vswz = (l15 ^ (l15 >> 2)) & 3;
    int sgrp = q * 8;

    float mn = mnmx[h * 2], mx = mnmx[h * 2 + 1];
    float x2[2], mref2[2];
    #pragma unroll
    for (int r = 0; r < 2; ++r) {
        int m = m0 + r * 16 + l15;
        int tt = m % T_LEN;
        int rr = m / T_LEN;
        int b = rr >> 4, n = rr & 15;
        float v = ts[((size_t)b * T_LEN + tt) * N_VARS + n];
        if (v != v) v = 0.f;
        x2[r] = v;                                    // Kpad pre-scaled by 1/sqrt(128)/ln2
        mref2[r] = (v >= 0.f) ? v * mx : v * mn;      // exact max over s<1000
    }

    f32x4 acc[2][8];
    #pragma unroll
    for (int r = 0; r < 2; ++r)
        #pragma unroll
        for (int e = 0; e < 8; ++e) acc[r][e] = (f32x4){0.f, 0.f, 0.f, 0.f};
    f32x4 accd[2];
    accd[0] = (f32x4){0.f, 0.f, 0.f, 0.f};
    accd[1] = (f32x4){0.f, 0.f, 0.f, 0.f};
    short8 ones;
    #pragma unroll
    for (int j = 0; j < 8; ++j) ones[j] = (short)0x3F80;  // bf16 1.0

    const float* kvp = Kpad + h * S_PAD;
    int ci1 = tid + 256;
    const __hip_bfloat16* gsrc0 = Vt + (size_t)(h * DK + (tid >> 2)) * S_PAD + (tid & 3) * 8;
    const __hip_bfloat16* gsrc1 = Vt + (size_t)(h * DK + (ci1 >> 2)) * S_PAD + (ci1 & 3) * 8;
    char* ldsb = (char*)&Vs[0][0] + w * 1024;

    gload_lds16(gsrc0, ldsb);
    gload_lds16(gsrc1, ldsb + 4096);
    __syncthreads();

    for (int kt = 0; kt < 32; ++kt) {
        int cur = kt & 1;
        if (kt < 31) {
            char* d = ldsb + ((cur ^ 1) * 8192);
            gload_lds16(gsrc0 + (kt + 1) * 32, d);
            gload_lds16(gsrc1 + (kt + 1) * 32, d + 4096);
        }
        int s0 = kt * 32;
        float4 kA = *(const float4*)(kvp + s0 + sgrp);
        float4 kB = *(const float4*)(kvp + s0 + sgrp + 4);
        float kv[8] = {kA.x, kA.y, kA.z, kA.w, kB.x, kB.y, kB.z, kB.w};
        short8 afr[2];
        #pragma unroll
        for (int r = 0; r < 2; ++r) {
            #pragma unroll
            for (int j = 0; j < 8; ++j) {
                float wgt = __builtin_amdgcn_exp2f(fmaf(x2[r], kv[j], -mref2[r]));
                afr[r][j] = __builtin_bit_cast(short, __float2bfloat16(wgt));
            }
        }
        const char* vb = (const char*)&Vs[0][0] + cur * 8192 + l15 * 64 + ((q ^ vswz) << 4);
        #pragma unroll
        for (int e = 0; e < 8; ++e) {
            short8 bf = *(const short8*)(vb + e * 1024);
            acc[0][e] = __builtin_amdgcn_mfma_f32_16x16x32_bf16(afr[0], bf, acc[0][e], 0, 0, 0);
            acc[1][e] = __builtin_amdgcn_mfma_f32_16x16x32_bf16(afr[1], bf, acc[1][e], 0, 0, 0);
        }
        accd[0] = __builtin_amdgcn_mfma_f32_16x16x32_bf16(afr[0], ones, accd[0], 0, 0, 0);
        accd[1] = __builtin_amdgcn_mfma_f32_16x16x32_bf16(afr[1], ones, accd[1], 0, 0, 0);
        __syncthreads();
    }

    int rowoff = q << 2;
    #pragma unroll
    for (int r = 0; r < 2; ++r) {
        #pragma unroll
        for (int qq = 0; qq < 4; ++qq) {
            float mq = __shfl(mref2[r], rowoff + qq);
            float den = accd[r][qq] - 24.f * __builtin_amdgcn_exp2f(-mq);  // remove 24 pad terms
            float inv = 1.f / den;
            int mrow = m0 + r * 16 + rowoff + qq;
            __hip_bfloat16* op = attB + (size_t)mrow * DKH + h * DK + l15;
            #pragma unroll
            for (int e = 0; e < 8; ++e)
                op[e * 16] = __float2bfloat16(acc[r][e][qq] * inv);
        }
    }
}

// ---------------- out projection via MFMA, m97 staging + XCD-chunked swizzle ----------------
__global__ __launch_bounds__(256) void outproj_mfma_kernel(const __hip_bfloat16* __restrict__ A,
                                                           const __hip_bfloat16* __restrict__ Bt,
                                                           const float* __restrict__ bo,
                                                           float* __restrict__ C) {
    int wg = blockIdx.x;                       // 576 blocks, 576 % 8 == 0
    int wgs = (wg & 7) * 72 + (wg >> 3);       // bijective XCD chunking
    int bx = wgs % 6;
    int by = wgs / 6;

    __shared__ __hip_bfloat16 As[128 * 32];
    __shared__ __hip_bfloat16 Bs[128 * 32];
    int t = threadIdx.x;
    int w = t >> 6, lane = t & 63;
    int wr = w >> 1, wc = w & 1;
    int bm0 = by * 128;
    int bn0 = bx * 128;

    int lrow = t >> 2;
    int lcol = (t & 3) * 8;
    const __hip_bfloat16* ga0 = A + (size_t)(bm0 + lrow) * DKH + lcol;
    const __hip_bfloat16* ga1 = A + (size_t)(bm0 + 64 + lrow) * DKH + lcol;
    const __hip_bfloat16* gb0 = Bt + (size_t)(bn0 + lrow) * DKH + lcol;
    const __hip_bfloat16* gb1 = Bt + (size_t)(bn0 + 64 + lrow) * DKH + lcol;
    char* lA = (char*)As + w * 1024;
    char* lB = (char*)Bs + w * 1024;

    f32x4 acc[4][4];
    #pragma unroll
    for (int m = 0; m < 4; ++m)
        #pragma unroll
        for (int n = 0; n < 4; ++n) acc[m][n] = (f32x4){0.f, 0.f, 0.f, 0.f};

    int sgrp = (lane >> 4) << 3;
    int arow = wr * 64 + (lane & 15);
    int brow = wc * 64 + (lane & 15);

    for (int k0 = 0; k0 < DKH; k0 += 32) {
        gload_lds16(ga0 + k0, lA);
        gload_lds16(ga1 + k0, lA + 4096);
        gload_lds16(gb0 + k0, lB);
        gload_lds16(gb1 + k0, lB + 4096);
        __syncthreads();
        short8 af[4], bf[4];
        #pragma unroll
        for (int m = 0; m < 4; ++m)
            af[m] = *(const short8*)(As + (size_t)(arow + m * 16) * 32 + sgrp);
        #pragma unroll
        for (int n = 0; n < 4; ++n)
            bf[n] = *(const short8*)(Bs + (size_t)(brow + n * 16) * 32 + sgrp);
        #pragma unroll
        for (int m = 0; m < 4; ++m)
            #pragma unroll
            for (int n = 0; n < 4; ++n)
                acc[m][n] = __builtin_amdgcn_mfma_f32_16x16x32_bf16(af[m], bf[n], acc[m][n], 0, 0, 0);
        __syncthreads();
    }

    int rowoff = (lane >> 4) << 2;
    #pragma unroll
    for (int m = 0; m < 4; ++m) {
        #pragma unroll
        for (int n = 0; n < 4; ++n) {
            int col = bn0 + wc * 64 + n * 16 + (lane & 15);
            float b = bo[col];
            #pragma unroll
            for (int q = 0; q < 4; ++q) {
                int row = bm0 + wr * 64 + m * 16 + rowoff + q;
                C[(size_t)row * D_LLM + col] = acc[m][n][q] + b;
            }
        }
    }
}

extern "C" void kernel_launch(void* const* d_in, const int* in_sizes, int n_in,
                              void* d_out, int out_size, void* d_ws, size_t ws_size,
                              hipStream_t stream) {
    const float* ts   = (const float*)d_in[0];
    const float* src  = (const float*)d_in[1];
    const float* vemb = (const float*)d_in[2];
    const float* Wk   = (const float*)d_in[3];
    const float* bk   = (const float*)d_in[4];
    const float* Wv   = (const float*)d_in[5];
    const float* bv   = (const float*)d_in[6];
    const float* Wo   = (const float*)d_in[7];
    const float* bo   = (const float*)d_in[8];
    float* out = (float*)d_out;

    // workspace layout (float offsets, 16B aligned); peak = 936960+6291456 floats ~ 28.9 MB
    float* ws = (float*)d_ws;
    float* Kpad   = ws;                                      // 8192 f
    float* Wksum  = ws + 8192;                               // 6144 f
    float* bksum  = ws + 14336;                              // 8 f
    float* mnmx   = ws + 14344;                              // 16 f
    __hip_bfloat16* Vt   = (__hip_bfloat16*)(ws + 14592);    // 1024*1024 bf16
    __hip_bfloat16* Wot  = (__hip_bfloat16*)(ws + 540672);   // 768*1024 bf16
    __hip_bfloat16* attB = (__hip_bfloat16*)(ws + 936960);   // 12288*1024 bf16
    // vproj prep buffers alias attB (dead before attn writes attB)
    __hip_bfloat16* Ab16 = (__hip_bfloat16*)(ws + 936960);   // 1024*768 bf16
    __hip_bfloat16* Wvt  = (__hip_bfloat16*)(ws + 1330176);  // 1024*768 bf16

    // 1) Wksum / bksum
    wksum_kernel<<<193, 256, 0, stream>>>(Wk, bk, Wksum, bksum);
    // 2) Kpad (scaled, zero-padded to 1024)
    ksum_kernel<<<256, 256, 0, stream>>>(src, Wksum, bksum, Kpad);
    // 3) min/max per head
    kminmax_kernel<<<8, 64, 0, stream>>>(Kpad, mnmx);
    // 4) vproj prep: vemb->bf16 (padded), Wv->Wvt bf16
    acvt_kernel<<<S_PAD, 192, 0, stream>>>(vemb, Ab16);
    {
        dim3 g(D_LLM / 32, DKH / 32);
        wvtrans_kernel<<<g, 256, 0, stream>>>(Wv, Wvt);
    }
    // 5) Wo transpose -> bf16
    {
        dim3 g(DKH / 32, D_LLM / 32);
        wtrans_kernel<<<g, 256, 0, stream>>>(Wo, Wot);
    }
    // 6) V projection (MFMA) -> swizzled-transposed Vt bf16
    {
        dim3 g(DKH / 128, S_PAD / 128);
        vproj_mfma_kernel<<<g, 256, 0, stream>>>(Ab16, Wvt, bv, Vt);
    }
    // 7) fused softmax + PV (MFMA, LDS double-buffered V)
    {
        dim3 g(96, NH);
        attn_mfma_kernel<<<g, 256, 0, stream>>>(ts, Kpad, mnmx, Vt, attB);
    }
    // 8) out projection (MFMA): [12288,1024] @ [1024,768] + bo
    outproj_mfma_kernel<<<576, 256, 0, stream>>>(attB, Wot, bo, out);
}

// Round 5
// 107.139 us; speedup vs baseline: 11.9659x; 1.1761x over previous
//
#include <hip/hip_runtime.h>
#include <hip/hip_bf16.h>
#include <math.h>

#define D_LLM 768
#define DKH   1024   // d_keys * n_heads = 128*8
#define NH    8
#define DK    128
#define S_LEN 1000
#define S_PAD 1024
#define M_ROWS 12288 // B*N*T = 128*96
#define T_LEN 96
#define N_VARS 16

static constexpr float SCALE_EXP2 = (float)(0.08838834764831845 * 1.4426950408889634); // 1/sqrt(128)/ln2

typedef __attribute__((ext_vector_type(8))) short short8;
typedef __attribute__((ext_vector_type(4))) float f32x4;

__device__ __forceinline__ void gload_lds16(const void* g, void* l) {
    __builtin_amdgcn_global_load_lds(
        (const __attribute__((address_space(1))) unsigned int*)g,
        (__attribute__((address_space(3))) unsigned int*)l, 16, 0, 0);
}

// ================= prep: vemb->bf16 | Wv^T->bf16 | Wo^T->bf16 | Wksum =================
__global__ __launch_bounds__(256) void prep_kernel(const float* __restrict__ vemb,
                                                   const float* __restrict__ Wv,
                                                   const float* __restrict__ Wo,
                                                   const float* __restrict__ Wk,
                                                   const float* __restrict__ bk,
                                                   __hip_bfloat16* __restrict__ Ab16,
                                                   __hip_bfloat16* __restrict__ Wvt,
                                                   __hip_bfloat16* __restrict__ Wot,
                                                   float* __restrict__ Wksum,
                                                   float* __restrict__ bksum) {
    __shared__ float tl[32][33];
    int blk = blockIdx.x, tid = threadIdx.x;
    if (blk < 768) {
        // vemb fp32[1000*768] -> bf16[1024*768], zero-padded
        int i4 = (blk * 256 + tid) * 4;
        float4 v = make_float4(0.f, 0.f, 0.f, 0.f);
        if (i4 < S_LEN * D_LLM) v = *(const float4*)(vemb + i4);
        short4 o;
        o.x = __builtin_bit_cast(short, __float2bfloat16(v.x));
        o.y = __builtin_bit_cast(short, __float2bfloat16(v.y));
        o.z = __builtin_bit_cast(short, __float2bfloat16(v.z));
        o.w = __builtin_bit_cast(short, __float2bfloat16(v.w));
        *(short4*)(Ab16 + i4) = o;
    } else if (blk < 1536) {
        // Wv fp32[768][1024] -> Wvt bf16[1024][768]
        int tau = blk - 768;
        int k0 = (tau % 24) * 32, n0 = (tau / 24) * 32;
        int tx = tid & 31, ty = tid >> 5;
        #pragma unroll
        for (int p = 0; p < 4; ++p)
            tl[ty + p * 8][tx] = Wv[(size_t)(k0 + ty + p * 8) * DKH + n0 + tx];
        __syncthreads();
        #pragma unroll
        for (int p = 0; p < 4; ++p)
            Wvt[(size_t)(n0 + ty + p * 8) * D_LLM + k0 + tx] = __float2bfloat16(tl[tx][ty + p * 8]);
    } else if (blk < 2304) {
        // Wo fp32[1024][768] -> Wot bf16[768][1024]
        int tau = blk - 1536;
        int k0 = (tau & 31) * 32, n0 = (tau >> 5) * 32;
        int tx = tid & 31, ty = tid >> 5;
        #pragma unroll
        for (int p = 0; p < 4; ++p)
            tl[ty + p * 8][tx] = Wo[(size_t)(k0 + ty + p * 8) * D_LLM + n0 + tx];
        __syncthreads();
        #pragma unroll
        for (int p = 0; p < 4; ++p)
            Wot[(size_t)(n0 + ty + p * 8) * DKH + k0 + tx] = __float2bfloat16(tl[tx][ty + p * 8]);
    } else {
        // Wksum / bksum
        int blk2 = blk - 2304;
        int w = tid >> 6, lane = tid & 63;
        if (blk2 < 192) {
            int d = blk2 * 4 + w;
            const float* p = Wk + (size_t)d * DKH + lane * 16;
            float s = 0.f;
            #pragma unroll
            for (int i = 0; i < 4; ++i) {
                float4 v = *(const float4*)(p + i * 4);
                s += v.x + v.y + v.z + v.w;
            }
            s += __shfl_down(s, 4);
            s += __shfl_down(s, 2);
            s += __shfl_down(s, 1);
            if ((lane & 7) == 0) Wksum[d * NH + (lane >> 3)] = s;
        } else if (w == 0) {
            const float* p = bk + lane * 16;
            float s = 0.f;
            #pragma unroll
            for (int i = 0; i < 4; ++i) {
                float4 v = *(const float4*)(p + i * 4);
                s += v.x + v.y + v.z + v.w;
            }
            s += __shfl_down(s, 4);
            s += __shfl_down(s, 2);
            s += __shfl_down(s, 1);
            if ((lane & 7) == 0) bksum[lane >> 3] = s;
        }
    }
}

// ---------------- Kpad[h][s] = (src[s,:].Wksum[:,h] + bksum[h]) * SCALE_EXP2 (s>=1000 -> 0) ----------------
__global__ __launch_bounds__(256) void ksum_kernel(const float* __restrict__ src,
                                                   const float* __restrict__ Wksum,
                                                   const float* __restrict__ bksum,
                                                   float* __restrict__ Kpad) {
    int w = threadIdx.x >> 6, lane = threadIdx.x & 63;
    int s = blockIdx.x * 4 + w;
    if (s >= S_LEN) {
        if (lane < 8) Kpad[lane * S_PAD + s] = 0.f;
        return;
    }
    const float* sp = src + (size_t)s * D_LLM + lane * 12;
    float xv[12];
    ((float4*)xv)[0] = *(const float4*)(sp);
    ((float4*)xv)[1] = *(const float4*)(sp + 4);
    ((float4*)xv)[2] = *(const float4*)(sp + 8);
    float a[8] = {0.f, 0.f, 0.f, 0.f, 0.f, 0.f, 0.f, 0.f};
    const float* wp = Wksum + lane * 12 * NH;
    #pragma unroll
    for (int i = 0; i < 12; ++i) {
        float4 wa = *(const float4*)(wp + i * 8);
        float4 wb = *(const float4*)(wp + i * 8 + 4);
        a[0] = fmaf(xv[i], wa.x, a[0]); a[1] = fmaf(xv[i], wa.y, a[1]);
        a[2] = fmaf(xv[i], wa.z, a[2]); a[3] = fmaf(xv[i], wa.w, a[3]);
        a[4] = fmaf(xv[i], wb.x, a[4]); a[5] = fmaf(xv[i], wb.y, a[5]);
        a[6] = fmaf(xv[i], wb.z, a[6]); a[7] = fmaf(xv[i], wb.w, a[7]);
    }
    #pragma unroll
    for (int off = 32; off > 0; off >>= 1) {
        #pragma unroll
        for (int hh = 0; hh < 8; ++hh) a[hh] += __shfl_xor(a[hh], off);
    }
    #pragma unroll
    for (int hh = 0; hh < 8; ++hh)
        if (lane == hh) Kpad[hh * S_PAD + s] = (a[hh] + bksum[hh]) * SCALE_EXP2;
}

// ================= double-buffered 128x128 MFMA GEMM (prefetch-before-compute) =================
// C[M,N] = A_bf16[M,KD] @ Bt_bf16[N,KD]^T ; VP: write transposed bf16 Vt w/ zero pad; else fp32 + bias
template <int KD, int AS, int BS, int NBX, int CPX, bool VP>
__global__ __launch_bounds__(256) void gemm_db_kernel(const __hip_bfloat16* __restrict__ A,
                                                      const __hip_bfloat16* __restrict__ Bt,
                                                      const float* __restrict__ bias,
                                                      void* __restrict__ Cout) {
    __shared__ __hip_bfloat16 As[2][128 * 32];
    __shared__ __hip_bfloat16 Bs[2][128 * 32];
    int wg = blockIdx.x;
    if (CPX > 0) wg = (wg & 7) * CPX + (wg >> 3);
    int bx = wg % NBX, by = wg / NBX;
    int t = threadIdx.x;
    int w = t >> 6, lane = t & 63;
    int wr = w >> 1, wc = w & 1;
    int bm0 = by * 128, bn0 = bx * 128;
    int lrow = t >> 2, lcol = (t & 3) * 8;
    const __hip_bfloat16* ga0 = A + (size_t)(bm0 + lrow) * AS + lcol;
    const __hip_bfloat16* ga1 = ga0 + (size_t)64 * AS;
    const __hip_bfloat16* gb0 = Bt + (size_t)(bn0 + lrow) * BS + lcol;
    const __hip_bfloat16* gb1 = gb0 + (size_t)64 * BS;

    f32x4 acc[4][4];
    #pragma unroll
    for (int m = 0; m < 4; ++m)
        #pragma unroll
        for (int n = 0; n < 4; ++n) acc[m][n] = (f32x4){0.f, 0.f, 0.f, 0.f};

    int sgrp = (lane >> 4) << 3;
    int arow = wr * 64 + (lane & 15);
    int brow = wc * 64 + (lane & 15);

#define STAGE_G(buf, k0) do { \
        gload_lds16(ga0 + (k0), (char*)&As[buf][0] + w * 1024); \
        gload_lds16(ga1 + (k0), (char*)&As[buf][0] + 4096 + w * 1024); \
        gload_lds16(gb0 + (k0), (char*)&Bs[buf][0] + w * 1024); \
        gload_lds16(gb1 + (k0), (char*)&Bs[buf][0] + 4096 + w * 1024); } while (0)

    STAGE_G(0, 0);
    __syncthreads();
    constexpr int NT = KD / 32;
    #pragma unroll 2
    for (int tt = 0; tt < NT; ++tt) {
        int cur = tt & 1;
        if (tt + 1 < NT) STAGE_G(cur ^ 1, (tt + 1) * 32);
        const __hip_bfloat16* Ac = &As[0][0] + cur * (128 * 32);
        const __hip_bfloat16* Bc = &Bs[0][0] + cur * (128 * 32);
        short8 af[4], bf[4];
        #pragma unroll
        for (int m = 0; m < 4; ++m)
            af[m] = *(const short8*)(Ac + (size_t)(arow + m * 16) * 32 + sgrp);
        #pragma unroll
        for (int n = 0; n < 4; ++n)
            bf[n] = *(const short8*)(Bc + (size_t)(brow + n * 16) * 32 + sgrp);
        __builtin_amdgcn_s_setprio(1);
        #pragma unroll
        for (int m = 0; m < 4; ++m)
            #pragma unroll
            for (int n = 0; n < 4; ++n)
                acc[m][n] = __builtin_amdgcn_mfma_f32_16x16x32_bf16(af[m], bf[n], acc[m][n], 0, 0, 0);
        __builtin_amdgcn_s_setprio(0);
        __syncthreads();
    }
#undef STAGE_G

    int rowoff = (lane >> 4) << 2;
    if (VP) {
        __hip_bfloat16* Vt = (__hip_bfloat16*)Cout;
        #pragma unroll
        for (int m = 0; m < 4; ++m) {
            #pragma unroll
            for (int n = 0; n < 4; ++n) {
                int c = bn0 + wc * 64 + n * 16 + (lane & 15);
                float b = bias[c];
                #pragma unroll
                for (int q = 0; q < 4; ++q) {
                    int srow = bm0 + wr * 64 + m * 16 + rowoff + q;
                    float val = (srow < S_LEN) ? acc[m][n][q] + b : 0.f;
                    Vt[(size_t)c * S_PAD + srow] = __float2bfloat16(val);
                }
            }
        }
    } else {
        float* C = (float*)Cout;
        #pragma unroll
        for (int m = 0; m < 4; ++m) {
            #pragma unroll
            for (int n = 0; n < 4; ++n) {
                int col = bn0 + wc * 64 + n * 16 + (lane & 15);
                float b = bias[col];
                #pragma unroll
                for (int q = 0; q < 4; ++q) {
                    int row = bm0 + wr * 64 + m * 16 + rowoff + q;
                    C[(size_t)row * D_LLM + col] = acc[m][n][q] + b;
                }
            }
        }
    }
}

// ================= fused softmax + PV, counted-vmcnt pipeline =================
__device__ __forceinline__ void compute_afr(const float* kq, float x0, float x1,
                                            short8& o0, short8& o1) {
    float4 a = *(const float4*)kq;
    float4 b = *(const float4*)(kq + 4);
    float kv[8] = {a.x, a.y, a.z, a.w, b.x, b.y, b.z, b.w};
    #pragma unroll
    for (int j = 0; j < 8; ++j) {
        float w0 = __builtin_amdgcn_exp2f(x0 * kv[j]);
        float w1 = __builtin_amdgcn_exp2f(x1 * kv[j]);
        o0[j] = (short)((__builtin_bit_cast(unsigned, w0) + 0x8000u) >> 16);
        o1[j] = (short)((__builtin_bit_cast(unsigned, w1) + 0x8000u) >> 16);
    }
}

__global__ __launch_bounds__(256) void attn_mfma_kernel(const float* __restrict__ ts,
                                                        const float* __restrict__ Kpad,
                                                        const __hip_bfloat16* __restrict__ Vt,
                                                        __hip_bfloat16* __restrict__ attB) {
    __shared__ __hip_bfloat16 Vs[2][8192];   // 2 x 16KB chunks (64 s x 128 e, XOR-swizzled rows)
    const int tid = threadIdx.x;
    const int lane = tid & 63, w = tid >> 6;
    const int h = blockIdx.y;
    const int m0 = (blockIdx.x * 4 + w) * 32;
    const int l15 = lane & 15, q = lane >> 4;

    // staging: instr i covers e-rows i*32 + w*8 + (lane>>3); source s pre-swizzled so linear
    // LDS dest + XOR'd read agree (m173 pattern)
    const int erow = w * 8 + (lane >> 3);
    const int sgl = ((lane & 7) ^ (lane >> 3)) * 8;
    const __hip_bfloat16* gsrc = Vt + (size_t)(h * DK + erow) * S_PAD + sgl;

    float x0, x1;
    {
        int m = m0 + l15;
        int rr = m / T_LEN;
        float v = ts[((size_t)(rr >> 4) * T_LEN + (m % T_LEN)) * N_VARS + (rr & 15)];
        x0 = (v != v) ? 0.f : v;
        m = m0 + 16 + l15;
        rr = m / T_LEN;
        v = ts[((size_t)(rr >> 4) * T_LEN + (m % T_LEN)) * N_VARS + (rr & 15)];
        x1 = (v != v) ? 0.f : v;
    }

    f32x4 acc0[8], acc1[8];
    #pragma unroll
    for (int e = 0; e < 8; ++e) {
        acc0[e] = (f32x4){0.f, 0.f, 0.f, 0.f};
        acc1[e] = (f32x4){0.f, 0.f, 0.f, 0.f};
    }
    f32x4 accd0 = (f32x4){0.f, 0.f, 0.f, 0.f};
    f32x4 accd1 = (f32x4){0.f, 0.f, 0.f, 0.f};
    short8 ones;
    #pragma unroll
    for (int j = 0; j < 8; ++j) ones[j] = (short)0x3F80;

    const float* kvp = Kpad + h * S_PAD + q * 8;
    short8 afrA0, afrA1, afrB0, afrB1;
    compute_afr(kvp, x0, x1, afrA0, afrA1);

    // prologue: stage chunk0 + chunk1 (4 gloads each, per wave)
    #pragma unroll
    for (int i = 0; i < 4; ++i)
        gload_lds16(gsrc + (size_t)(i * 32) * S_PAD, (char*)&Vs[0][0] + i * 4096 + w * 1024);
    #pragma unroll
    for (int i = 0; i < 4; ++i)
        gload_lds16(gsrc + (size_t)(i * 32) * S_PAD + 64, (char*)&Vs[1][0] + i * 4096 + w * 1024);
    asm volatile("s_waitcnt vmcnt(4)" ::: "memory");
    __builtin_amdgcn_s_barrier();

    const int bofs0 = l15 * 128 + ((q * 16) ^ ((l15 & 7) << 4));
    const int bofs1 = l15 * 128 + ((64 + q * 16) ^ ((l15 & 7) << 4));

#define PVSTEP(AF0, AF1, BOFS) do { \
        __builtin_amdgcn_s_setprio(1); \
        _Pragma("unroll") \
        for (int e = 0; e < 8; ++e) { \
            short8 bfv = *(const short8*)(cb + e * 2048 + (BOFS)); \
            acc0[e] = __builtin_amdgcn_mfma_f32_16x16x32_bf16(AF0, bfv, acc0[e], 0, 0, 0); \
            acc1[e] = __builtin_amdgcn_mfma_f32_16x16x32_bf16(AF1, bfv, acc1[e], 0, 0, 0); \
        } \
        accd0 = __builtin_amdgcn_mfma_f32_16x16x32_bf16(AF0, ones, accd0, 0, 0, 0); \
        accd1 = __builtin_amdgcn_mfma_f32_16x16x32_bf16(AF1, ones, accd1, 0, 0, 0); \
        __builtin_amdgcn_s_setprio(0); } while (0)

    #pragma unroll 2
    for (int kt = 0; kt < 16; ++kt) {
        const char* cb = (const char*)&Vs[0][0] + (kt & 1) * 16384;
        // sub0 (s = kt*64 .. +31) with afrA; compute afrB for sub1 meanwhile
        compute_afr(kvp + kt * 64 + 32, x0, x1, afrB0, afrB1);
        PVSTEP(afrA0, afrA1, bofs0);
        // sub1 with afrB; compute afrA for next chunk meanwhile
        if (kt < 15) compute_afr(kvp + (kt + 1) * 64, x0, x1, afrA0, afrA1);
        PVSTEP(afrB0, afrB1, bofs1);
        __builtin_amdgcn_s_barrier();          // all waves done reading buf[kt&1]
        if (kt < 14) {
            #pragma unroll
            for (int i = 0; i < 4; ++i)
                gload_lds16(gsrc + (size_t)(i * 32) * S_PAD + (kt + 2) * 64,
                            (char*)&Vs[0][0] + (kt & 1) * 16384 + i * 4096 + w * 1024);
            asm volatile("s_waitcnt vmcnt(4)" ::: "memory");   // chunk kt+1 landed
        } else {
            asm volatile("s_waitcnt vmcnt(0)" ::: "memory");
        }
        __builtin_amdgcn_s_barrier();
    }
#undef PVSTEP

    // epilogue: den = rowsum - 24 pad terms (pads: kv=0 -> w=1 exactly)
    int rowoff = q << 2;
    #pragma unroll
    for (int r = 0; r < 2; ++r) {
        #pragma unroll
        for (int qq = 0; qq < 4; ++qq) {
            float den = (r ? accd1[qq] : accd0[qq]) - 24.f;
            float inv = 1.f / den;
            int mrow = m0 + r * 16 + rowoff + qq;
            __hip_bfloat16* op = attB + (size_t)mrow * DKH + h * DK + l15;
            #pragma unroll
            for (int e = 0; e < 8; ++e)
                op[e * 16] = __float2bfloat16((r ? acc1[e][qq] : acc0[e][qq]) * inv);
        }
    }
}

extern "C" void kernel_launch(void* const* d_in, const int* in_sizes, int n_in,
                              void* d_out, int out_size, void* d_ws, size_t ws_size,
                              hipStream_t stream) {
    const float* ts   = (const float*)d_in[0];
    const float* src  = (const float*)d_in[1];
    const float* vemb = (const float*)d_in[2];
    const float* Wk   = (const float*)d_in[3];
    const float* bk   = (const float*)d_in[4];
    const float* Wv   = (const float*)d_in[5];
    const float* bv   = (const float*)d_in[6];
    const float* Wo   = (const float*)d_in[7];
    const float* bo   = (const float*)d_in[8];
    float* out = (float*)d_out;

    // workspace layout (float offsets, 16B aligned)
    float* ws = (float*)d_ws;
    float* Kpad   = ws;                                      // 8192 f
    float* Wksum  = ws + 8192;                               // 6144 f
    float* bksum  = ws + 14336;                              // 16 f
    __hip_bfloat16* Vt   = (__hip_bfloat16*)(ws + 14592);    // 1024*1024 bf16
    __hip_bfloat16* Wot  = (__hip_bfloat16*)(ws + 540672);   // 768*1024 bf16
    __hip_bfloat16* attB = (__hip_bfloat16*)(ws + 936960);   // 12288*1024 bf16
    // vproj prep buffers alias attB region (dead before attn writes attB)
    __hip_bfloat16* Ab16 = (__hip_bfloat16*)(ws + 936960);   // 1024*768 bf16
    __hip_bfloat16* Wvt  = (__hip_bfloat16*)(ws + 1330176);  // 1024*768 bf16

    // 1) prep: vemb->bf16, Wv^T, Wo^T, Wksum/bksum
    prep_kernel<<<2497, 256, 0, stream>>>(vemb, Wv, Wo, Wk, bk, Ab16, Wvt, Wot, Wksum, bksum);
    // 2) Kpad (scaled by 1/sqrt(128)/ln2, zero-padded to 1024)
    ksum_kernel<<<256, 256, 0, stream>>>(src, Wksum, bksum, Kpad);
    // 3) V projection (MFMA, double-buffered) -> transposed Vt bf16 [c][s]
    gemm_db_kernel<768, 768, 768, 8, 8, true><<<64, 256, 0, stream>>>(Ab16, Wvt, bv, (void*)Vt);
    // 4) fused softmax + PV (MFMA, counted-vmcnt pipeline)
    {
        dim3 g(96, NH);
        attn_mfma_kernel<<<g, 256, 0, stream>>>(ts, Kpad, Vt, attB);
    }
    // 5) out projection (MFMA, double-buffered, XCD-swizzled): [12288,1024]@[1024,768] + bo
    gemm_db_kernel<1024, 1024, 1024, 6, 72, false><<<576, 256, 0, stream>>>(attB, Wot, bo, (void*)out);
}

// Round 7
// 100.807 us; speedup vs baseline: 12.7175x; 1.0628x over previous
//
#include <hip/hip_runtime.h>
#include <hip/hip_bf16.h>
#include <math.h>

#define D_LLM 768
#define DKH   1024   // d_keys * n_heads = 128*8
#define NH    8
#define DK    128
#define S_LEN 1000
#define S_PAD 1024
#define M_ROWS 12288 // B*N*T = 128*96
#define T_LEN 96
#define N_VARS 16

static constexpr float SCALE_EXP2 = (float)(0.08838834764831845 * 1.4426950408889634); // 1/sqrt(128)/ln2

typedef __attribute__((ext_vector_type(8))) _Float16 half8;
typedef __attribute__((ext_vector_type(2))) _Float16 half2v;
typedef __attribute__((ext_vector_type(4))) float f32x4;

__device__ __forceinline__ half2v pkrtz(float a, float b) {
    return __builtin_bit_cast(half2v, __builtin_amdgcn_cvt_pkrtz(a, b));
}

__device__ __forceinline__ void gload_lds16(const void* g, void* l) {
    __builtin_amdgcn_global_load_lds(
        (const __attribute__((address_space(1))) unsigned int*)g,
        (__attribute__((address_space(3))) unsigned int*)l, 16, 0, 0);
}

// ================= prep: vemb->f16 | Wv^T->f16 | Wo^T->f16 | Wksum =================
__global__ __launch_bounds__(256) void prep_kernel(const float* __restrict__ vemb,
                                                   const float* __restrict__ Wv,
                                                   const float* __restrict__ Wo,
                                                   const float* __restrict__ Wk,
                                                   const float* __restrict__ bk,
                                                   _Float16* __restrict__ Ab16,
                                                   _Float16* __restrict__ Wvt,
                                                   _Float16* __restrict__ Wot,
                                                   float* __restrict__ Wksum,
                                                   float* __restrict__ bksum) {
    __shared__ float tl[32][33];
    int blk = blockIdx.x, tid = threadIdx.x;
    if (blk < 768) {
        // vemb fp32[1000*768] -> f16[1024*768], zero-padded
        int i4 = (blk * 256 + tid) * 4;
        float4 v = make_float4(0.f, 0.f, 0.f, 0.f);
        if (i4 < S_LEN * D_LLM) v = *(const float4*)(vemb + i4);
        short4 o;
        o.x = __builtin_bit_cast(short, (_Float16)v.x);
        o.y = __builtin_bit_cast(short, (_Float16)v.y);
        o.z = __builtin_bit_cast(short, (_Float16)v.z);
        o.w = __builtin_bit_cast(short, (_Float16)v.w);
        *(short4*)(Ab16 + i4) = o;
    } else if (blk < 1536) {
        // Wv fp32[768][1024] -> Wvt f16[1024][768]
        int tau = blk - 768;
        int k0 = (tau % 24) * 32, n0 = (tau / 24) * 32;
        int tx = tid & 31, ty = tid >> 5;
        #pragma unroll
        for (int p = 0; p < 4; ++p)
            tl[ty + p * 8][tx] = Wv[(size_t)(k0 + ty + p * 8) * DKH + n0 + tx];
        __syncthreads();
        #pragma unroll
        for (int p = 0; p < 4; ++p)
            Wvt[(size_t)(n0 + ty + p * 8) * D_LLM + k0 + tx] = (_Float16)tl[tx][ty + p * 8];
    } else if (blk < 2304) {
        // Wo fp32[1024][768] -> Wot f16[768][1024]
        int tau = blk - 1536;
        int k0 = (tau & 31) * 32, n0 = (tau >> 5) * 32;
        int tx = tid & 31, ty = tid >> 5;
        #pragma unroll
        for (int p = 0; p < 4; ++p)
            tl[ty + p * 8][tx] = Wo[(size_t)(k0 + ty + p * 8) * D_LLM + n0 + tx];
        __syncthreads();
        #pragma unroll
        for (int p = 0; p < 4; ++p)
            Wot[(size_t)(n0 + ty + p * 8) * DKH + k0 + tx] = (_Float16)tl[tx][ty + p * 8];
    } else {
        // Wksum / bksum
        int blk2 = blk - 2304;
        int w = tid >> 6, lane = tid & 63;
        if (blk2 < 192) {
            int d = blk2 * 4 + w;
            const float* p = Wk + (size_t)d * DKH + lane * 16;
            float s = 0.f;
            #pragma unroll
            for (int i = 0; i < 4; ++i) {
                float4 v = *(const float4*)(p + i * 4);
                s += v.x + v.y + v.z + v.w;
            }
            s += __shfl_down(s, 4);
            s += __shfl_down(s, 2);
            s += __shfl_down(s, 1);
            if ((lane & 7) == 0) Wksum[d * NH + (lane >> 3)] = s;
        } else if (w == 0) {
            const float* p = bk + lane * 16;
            float s = 0.f;
            #pragma unroll
            for (int i = 0; i < 4; ++i) {
                float4 v = *(const float4*)(p + i * 4);
                s += v.x + v.y + v.z + v.w;
            }
            s += __shfl_down(s, 4);
            s += __shfl_down(s, 2);
            s += __shfl_down(s, 1);
            if ((lane & 7) == 0) bksum[lane >> 3] = s;
        }
    }
}

// ---------------- Kpad[h][s] = (src[s,:].Wksum[:,h] + bksum[h]) * SCALE_EXP2 (s>=1000 -> 0) ----------------
__global__ __launch_bounds__(256) void ksum_kernel(const float* __restrict__ src,
                                                   const float* __restrict__ Wksum,
                                                   const float* __restrict__ bksum,
                                                   float* __restrict__ Kpad) {
    int w = threadIdx.x >> 6, lane = threadIdx.x & 63;
    int s = blockIdx.x * 4 + w;
    if (s >= S_LEN) {
        if (lane < 8) Kpad[lane * S_PAD + s] = 0.f;
        return;
    }
    const float* sp = src + (size_t)s * D_LLM + lane * 12;
    float xv[12];
    ((float4*)xv)[0] = *(const float4*)(sp);
    ((float4*)xv)[1] = *(const float4*)(sp + 4);
    ((float4*)xv)[2] = *(const float4*)(sp + 8);
    float a[8] = {0.f, 0.f, 0.f, 0.f, 0.f, 0.f, 0.f, 0.f};
    const float* wp = Wksum + lane * 12 * NH;
    #pragma unroll
    for (int i = 0; i < 12; ++i) {
        float4 wa = *(const float4*)(wp + i * 8);
        float4 wb = *(const float4*)(wp + i * 8 + 4);
        a[0] = fmaf(xv[i], wa.x, a[0]); a[1] = fmaf(xv[i], wa.y, a[1]);
        a[2] = fmaf(xv[i], wa.z, a[2]); a[3] = fmaf(xv[i], wa.w, a[3]);
        a[4] = fmaf(xv[i], wb.x, a[4]); a[5] = fmaf(xv[i], wb.y, a[5]);
        a[6] = fmaf(xv[i], wb.z, a[6]); a[7] = fmaf(xv[i], wb.w, a[7]);
    }
    #pragma unroll
    for (int off = 32; off > 0; off >>= 1) {
        #pragma unroll
        for (int hh = 0; hh < 8; ++hh) a[hh] += __shfl_xor(a[hh], off);
    }
    #pragma unroll
    for (int hh = 0; hh < 8; ++hh)
        if (lane == hh) Kpad[hh * S_PAD + s] = (a[hh] + bksum[hh]) * SCALE_EXP2;
}

// ---------------- per-head min/max of Kpad over s<1000 (scaled units) ----------------
__global__ __launch_bounds__(64) void kminmax_kernel(const float* __restrict__ Kpad,
                                                     float* __restrict__ mnmx) {
    int h = blockIdx.x, lane = threadIdx.x;
    float mx = -1e30f, mn = 1e30f;
    for (int s = lane; s < S_LEN; s += 64) {
        float v = Kpad[h * S_PAD + s];
        mx = fmaxf(mx, v); mn = fminf(mn, v);
    }
    #pragma unroll
    for (int off = 32; off > 0; off >>= 1) {
        mx = fmaxf(mx, __shfl_xor(mx, off));
        mn = fminf(mn, __shfl_xor(mn, off));
    }
    if (lane == 0) { mnmx[h * 2] = mn; mnmx[h * 2 + 1] = mx; }
}

// ================= V projection, 64x64 tiles (grid 256 = 1 block/CU) =================
// Vt[c][s] = f16(vemb@Wv + bv), zero-padded s>=1000
__global__ __launch_bounds__(256) void vproj_kernel(const _Float16* __restrict__ A,
                                                    const _Float16* __restrict__ Bt,
                                                    const float* __restrict__ bias,
                                                    _Float16* __restrict__ Vt) {
    __shared__ _Float16 As[2][64 * 32];
    __shared__ _Float16 Bs[2][64 * 32];
    int t = threadIdx.x, w = t >> 6, lane = t & 63;
    int bm0 = (blockIdx.x >> 4) * 64, bn0 = (blockIdx.x & 15) * 64;
    int lrow = t >> 2, lcol = (t & 3) * 8;
    const _Float16* ga = A + (size_t)(bm0 + lrow) * D_LLM + lcol;
    const _Float16* gb = Bt + (size_t)(bn0 + lrow) * D_LLM + lcol;

    f32x4 acc[2][2];
    #pragma unroll
    for (int m = 0; m < 2; ++m)
        #pragma unroll
        for (int n = 0; n < 2; ++n) acc[m][n] = (f32x4){0.f, 0.f, 0.f, 0.f};
    int sgrp = (lane >> 4) << 3;
    int arow = (w >> 1) * 32 + (lane & 15);
    int brow = (w & 1) * 32 + (lane & 15);

#define VSTAGE(buf, k0) do { \
        gload_lds16(ga + (k0), (char*)&As[buf][0] + w * 1024); \
        gload_lds16(gb + (k0), (char*)&Bs[buf][0] + w * 1024); } while (0)

    VSTAGE(0, 0);
    __syncthreads();
    #pragma unroll 2
    for (int tt = 0; tt < 24; ++tt) {
        int cur = tt & 1;
        if (tt < 23) VSTAGE(cur ^ 1, (tt + 1) * 32);
        const _Float16* Ac = &As[cur][0];
        const _Float16* Bc = &Bs[cur][0];
        half8 af[2], bf[2];
        #pragma unroll
        for (int m = 0; m < 2; ++m) af[m] = *(const half8*)(Ac + (arow + m * 16) * 32 + sgrp);
        #pragma unroll
        for (int n = 0; n < 2; ++n) bf[n] = *(const half8*)(Bc + (brow + n * 16) * 32 + sgrp);
        __builtin_amdgcn_s_setprio(1);
        #pragma unroll
        for (int m = 0; m < 2; ++m)
            #pragma unroll
            for (int n = 0; n < 2; ++n)
                acc[m][n] = __builtin_amdgcn_mfma_f32_16x16x32_f16(af[m], bf[n], acc[m][n], 0, 0, 0);
        __builtin_amdgcn_s_setprio(0);
        __syncthreads();
    }
#undef VSTAGE

    int rowoff = (lane >> 4) << 2;
    #pragma unroll
    for (int m = 0; m < 2; ++m) {
        #pragma unroll
        for (int n = 0; n < 2; ++n) {
            int c = bn0 + (w & 1) * 32 + n * 16 + (lane & 15);
            float b = bias[c];
            #pragma unroll
            for (int q = 0; q < 4; ++q) {
                int srow = bm0 + (w >> 1) * 32 + m * 16 + rowoff + q;
                float val = (srow < S_LEN) ? acc[m][n][q] + b : 0.f;
                Vt[(size_t)c * S_PAD + srow] = (_Float16)val;
            }
        }
    }
}

// ================= fused softmax + PV (f16 MFMA, counted-vmcnt pipeline) =================
__device__ __forceinline__ void compute_afr(const float* kq, float x0, float x1,
                                            float nm0, float nm1, half8& o0, half8& o1) {
    float4 a = *(const float4*)kq;
    float4 b = *(const float4*)(kq + 4);
    float kv[8] = {a.x, a.y, a.z, a.w, b.x, b.y, b.z, b.w};
    union { half8 v; half2v h[4]; } u0, u1;
    #pragma unroll
    for (int j = 0; j < 4; ++j) {
        float w00 = __builtin_amdgcn_exp2f(fmaf(x0, kv[2 * j], nm0));
        float w01 = __builtin_amdgcn_exp2f(fmaf(x0, kv[2 * j + 1], nm0));
        u0.h[j] = pkrtz(w00, w01);
        float w10 = __builtin_amdgcn_exp2f(fmaf(x1, kv[2 * j], nm1));
        float w11 = __builtin_amdgcn_exp2f(fmaf(x1, kv[2 * j + 1], nm1));
        u1.h[j] = pkrtz(w10, w11);
    }
    o0 = u0.v; o1 = u1.v;
}

__global__ __launch_bounds__(256) void attn_mfma_kernel(const float* __restrict__ ts,
                                                        const float* __restrict__ Kpad,
                                                        const float* __restrict__ mnmx,
                                                        const _Float16* __restrict__ Vt,
                                                        _Float16* __restrict__ attB) {
    __shared__ _Float16 Vs[2][8192];   // 2 x 16KB chunks (64 s x 128 e, XOR-swizzled rows)
    const int tid = threadIdx.x;
    const int lane = tid & 63, w = tid >> 6;
    const int h = blockIdx.y;
    const int m0 = (blockIdx.x * 4 + w) * 32;
    const int l15 = lane & 15, q = lane >> 4;

    const int erow = w * 8 + (lane >> 3);
    const int sgl = ((lane & 7) ^ (lane >> 3)) * 8;
    const _Float16* gsrc = Vt + (size_t)(h * DK + erow) * S_PAD + sgl;

    float mn = mnmx[h * 2], mx = mnmx[h * 2 + 1];
    float x0, x1, nm0, nm1;
    {
        int m = m0 + l15;
        int rr = m / T_LEN;
        float v = ts[((size_t)(rr >> 4) * T_LEN + (m % T_LEN)) * N_VARS + (rr & 15)];
        x0 = (v != v) ? 0.f : v;
        nm0 = -((x0 >= 0.f) ? x0 * mx : x0 * mn);
        m = m0 + 16 + l15;
        rr = m / T_LEN;
        v = ts[((size_t)(rr >> 4) * T_LEN + (m % T_LEN)) * N_VARS + (rr & 15)];
        x1 = (v != v) ? 0.f : v;
        nm1 = -((x1 >= 0.f) ? x1 * mx : x1 * mn);
    }
    // pad weight per row, rounded exactly as the MFMA saw it (rtz f16)
    float wpadf0, wpadf1;
    {
        half2v p0 = pkrtz(__builtin_amdgcn_exp2f(nm0), 0.f);
        half2v p1 = pkrtz(__builtin_amdgcn_exp2f(nm1), 0.f);
        wpadf0 = (float)p0[0];
        wpadf1 = (float)p1[0];
    }

    f32x4 acc0[8], acc1[8];
    #pragma unroll
    for (int e = 0; e < 8; ++e) {
        acc0[e] = (f32x4){0.f, 0.f, 0.f, 0.f};
        acc1[e] = (f32x4){0.f, 0.f, 0.f, 0.f};
    }
    f32x4 accd0 = (f32x4){0.f, 0.f, 0.f, 0.f};
    f32x4 accd1 = (f32x4){0.f, 0.f, 0.f, 0.f};
    half8 ones;
    #pragma unroll
    for (int j = 0; j < 8; ++j) ones[j] = (_Float16)1.0f;

    const float* kvp = Kpad + h * S_PAD + q * 8;
    half8 afrA0, afrA1, afrB0, afrB1;
    compute_afr(kvp, x0, x1, nm0, nm1, afrA0, afrA1);

    #pragma unroll
    for (int i = 0; i < 4; ++i)
        gload_lds16(gsrc + (size_t)(i * 32) * S_PAD, (char*)&Vs[0][0] + i * 4096 + w * 1024);
    #pragma unroll
    for (int i = 0; i < 4; ++i)
        gload_lds16(gsrc + (size_t)(i * 32) * S_PAD + 64, (char*)&Vs[1][0] + i * 4096 + w * 1024);
    asm volatile("s_waitcnt vmcnt(4)" ::: "memory");
    __builtin_amdgcn_s_barrier();

    const int bofs0 = l15 * 128 + ((q * 16) ^ ((l15 & 7) << 4));
    const int bofs1 = l15 * 128 + ((64 + q * 16) ^ ((l15 & 7) << 4));

#define PVSTEP(AF0, AF1, BOFS) do { \
        __builtin_amdgcn_s_setprio(1); \
        _Pragma("unroll") \
        for (int e = 0; e < 8; ++e) { \
            half8 bfv = *(const half8*)(cb + e * 2048 + (BOFS)); \
            acc0[e] = __builtin_amdgcn_mfma_f32_16x16x32_f16(AF0, bfv, acc0[e], 0, 0, 0); \
            acc1[e] = __builtin_amdgcn_mfma_f32_16x16x32_f16(AF1, bfv, acc1[e], 0, 0, 0); \
        } \
        accd0 = __builtin_amdgcn_mfma_f32_16x16x32_f16(AF0, ones, accd0, 0, 0, 0); \
        accd1 = __builtin_amdgcn_mfma_f32_16x16x32_f16(AF1, ones, accd1, 0, 0, 0); \
        __builtin_amdgcn_s_setprio(0); } while (0)

    #pragma unroll 2
    for (int kt = 0; kt < 16; ++kt) {
        const char* cb = (const char*)&Vs[0][0] + (kt & 1) * 16384;
        compute_afr(kvp + kt * 64 + 32, x0, x1, nm0, nm1, afrB0, afrB1);
        PVSTEP(afrA0, afrA1, bofs0);
        if (kt < 15) compute_afr(kvp + (kt + 1) * 64, x0, x1, nm0, nm1, afrA0, afrA1);
        PVSTEP(afrB0, afrB1, bofs1);
        __builtin_amdgcn_s_barrier();
        if (kt < 14) {
            #pragma unroll
            for (int i = 0; i < 4; ++i)
                gload_lds16(gsrc + (size_t)(i * 32) * S_PAD + (kt + 2) * 64,
                            (char*)&Vs[0][0] + (kt & 1) * 16384 + i * 4096 + w * 1024);
            asm volatile("s_waitcnt vmcnt(4)" ::: "memory");
        } else {
            asm volatile("s_waitcnt vmcnt(0)" ::: "memory");
        }
        __builtin_amdgcn_s_barrier();
    }
#undef PVSTEP

    // epilogue: den = rowsum - 24 * wpad(row)
    int rowoff = q << 2;
    #pragma unroll
    for (int r = 0; r < 2; ++r) {
        #pragma unroll
        for (int qq = 0; qq < 4; ++qq) {
            float wp = __shfl(r ? wpadf1 : wpadf0, rowoff + qq);
            float den = (r ? accd1[qq] : accd0[qq]) - 24.f * wp;
            float inv = 1.f / den;
            int mrow = m0 + r * 16 + rowoff + qq;
            _Float16* op = attB + (size_t)mrow * DKH + h * DK + l15;
            #pragma unroll
            for (int e = 0; e < 8; ++e)
                op[e * 16] = (_Float16)((r ? acc1[e][qq] : acc0[e][qq]) * inv);
        }
    }
}

// ================= out projection, 128x96 tiles (grid 768 = 3 blocks/CU), XCD-swizzled =================
__global__ __launch_bounds__(256) void outproj_kernel(const _Float16* __restrict__ A,
                                                      const _Float16* __restrict__ Bt,
                                                      const float* __restrict__ bo,
                                                      float* __restrict__ C) {
    __shared__ _Float16 As[2][128 * 32];
    __shared__ _Float16 Bs[2][96 * 32];
    int wg = blockIdx.x;
    wg = (wg & 7) * 96 + (wg >> 3);            // bijective XCD chunking (768 % 8 == 0)
    int bx = wg & 7, by = wg >> 3;
    int t = threadIdx.x, w = t >> 6, lane = t & 63;
    int bm0 = by * 128, bn0 = bx * 96;
    int lrow = t >> 2, lcol = (t & 3) * 8;
    const _Float16* ga0 = A + (size_t)(bm0 + lrow) * DKH + lcol;
    const _Float16* ga1 = ga0 + (size_t)64 * DKH;
    const _Float16* gb0 = Bt + (size_t)(bn0 + lrow) * DKH + lcol;
    const _Float16* gb1 = gb0 + (size_t)64 * DKH;   // rows 64..95, threads < 128 only

    f32x4 acc[4][3];
    #pragma unroll
    for (int m = 0; m < 4; ++m)
        #pragma unroll
        for (int n = 0; n < 3; ++n) acc[m][n] = (f32x4){0.f, 0.f, 0.f, 0.f};

    int sgrp = (lane >> 4) << 3;
    int arow = (w >> 1) * 64 + (lane & 15);
    int brow = (w & 1) * 48 + (lane & 15);

#define OSTAGE(buf, k0) do { \
        gload_lds16(ga0 + (k0), (char*)&As[buf][0] + w * 1024); \
        gload_lds16(ga1 + (k0), (char*)&As[buf][0] + 4096 + w * 1024); \
        gload_lds16(gb0 + (k0), (char*)&Bs[buf][0] + w * 1024); \
        if (w < 2) gload_lds16(gb1 + (k0), (char*)&Bs[buf][0] + 4096 + w * 1024); } while (0)

    OSTAGE(0, 0);
    __syncthreads();
    #pragma unroll 2
    for (int tt = 0; tt < 32; ++tt) {
        int cur = tt & 1;
        if (tt < 31) OSTAGE(cur ^ 1, (tt + 1) * 32);
        const _Float16* Ac = &As[cur][0];
        const _Float16* Bc = &Bs[cur][0];
        half8 af[4], bf[3];
        #pragma unroll
        for (int m = 0; m < 4; ++m) af[m] = *(const half8*)(Ac + (arow + m * 16) * 32 + sgrp);
        #pragma unroll
        for (int n = 0; n < 3; ++n) bf[n] = *(const half8*)(Bc + (brow + n * 16) * 32 + sgrp);
        __builtin_amdgcn_s_setprio(1);
        #pragma unroll
        for (int m = 0; m < 4; ++m)
            #pragma unroll
            for (int n = 0; n < 3; ++n)
                acc[m][n] = __builtin_amdgcn_mfma_f32_16x16x32_f16(af[m], bf[n], acc[m][n], 0, 0, 0);
        __builtin_amdgcn_s_setprio(0);
        __syncthreads();
    }
#undef OSTAGE

    int rowoff = (lane >> 4) << 2;
    #pragma unroll
    for (int m = 0; m < 4; ++m) {
        #pragma unroll
        for (int n = 0; n < 3; ++n) {
            int col = bn0 + (w & 1) * 48 + n * 16 + (lane & 15);
            float b = bo[col];
            #pragma unroll
            for (int q = 0; q < 4; ++q) {
                int row = bm0 + (w >> 1) * 64 + m * 16 + rowoff + q;
                C[(size_t)row * D_LLM + col] = acc[m][n][q] + b;
            }
        }
    }
}

extern "C" void kernel_launch(void* const* d_in, const int* in_sizes, int n_in,
                              void* d_out, int out_size, void* d_ws, size_t ws_size,
                              hipStream_t stream) {
    const float* ts   = (const float*)d_in[0];
    const float* src  = (const float*)d_in[1];
    const float* vemb = (const float*)d_in[2];
    const float* Wk   = (const float*)d_in[3];
    const float* bk   = (const float*)d_in[4];
    const float* Wv   = (const float*)d_in[5];
    const float* bv   = (const float*)d_in[6];
    const float* Wo   = (const float*)d_in[7];
    const float* bo   = (const float*)d_in[8];
    float* out = (float*)d_out;

    // workspace layout (float offsets, 16B aligned)
    float* ws = (float*)d_ws;
    float* Kpad   = ws;                               // 8192 f
    float* Wksum  = ws + 8192;                        // 6144 f
    float* bksum  = ws + 14336;                       // 16 f
    float* mnmx   = ws + 14352;                       // 16 f
    _Float16* Vt   = (_Float16*)(ws + 14592);         // 1024*1024 f16
    _Float16* Wot  = (_Float16*)(ws + 540672);        // 768*1024 f16
    _Float16* attB = (_Float16*)(ws + 936960);        // 12288*1024 f16
    // vproj prep buffers alias attB region (dead before attn writes attB)
    _Float16* Ab16 = (_Float16*)(ws + 936960);        // 1024*768 f16
    _Float16* Wvt  = (_Float16*)(ws + 1330176);       // 1024*768 f16

    // 1) prep: vemb->f16, Wv^T, Wo^T, Wksum/bksum
    prep_kernel<<<2497, 256, 0, stream>>>(vemb, Wv, Wo, Wk, bk, Ab16, Wvt, Wot, Wksum, bksum);
    // 2) Kpad (scaled by 1/sqrt(128)/ln2, zero-padded to 1024)
    ksum_kernel<<<256, 256, 0, stream>>>(src, Wksum, bksum, Kpad);
    // 3) per-head min/max (for exact max-subtraction)
    kminmax_kernel<<<8, 64, 0, stream>>>(Kpad, mnmx);
    // 4) V projection (64x64 tiles, grid 256) -> transposed Vt f16 [c][s]
    vproj_kernel<<<256, 256, 0, stream>>>(Ab16, Wvt, bv, Vt);
    // 5) fused softmax + PV (f16 MFMA, counted-vmcnt pipeline)
    {
        dim3 g(96, NH);
        attn_mfma_kernel<<<g, 256, 0, stream>>>(ts, Kpad, mnmx, Vt, attB);
    }
    // 6) out projection (128x96 tiles, grid 768): [12288,1024]@[1024,768] + bo
    outproj_kernel<<<768, 256, 0, stream>>>(attB, Wot, bo, out);
}

// Round 8
// 88.184 us; speedup vs baseline: 14.5381x; 1.1432x over previous
//
#include <hip/hip_runtime.h>
#include <hip/hip_bf16.h>
#include <math.h>

#define D_LLM 768
#define DKH   1024   // d_keys * n_heads = 128*8
#define NH    8
#define DK    128
#define S_LEN 1000
#define S_PAD 1024
#define M_ROWS 12288 // B*N*T = 128*96
#define T_LEN 96
#define N_VARS 16

static constexpr float SCALE_EXP2 = (float)(0.08838834764831845 * 1.4426950408889634); // 1/sqrt(128)/ln2

typedef __attribute__((ext_vector_type(8))) _Float16 half8;
typedef __attribute__((ext_vector_type(2))) _Float16 half2v;
typedef __attribute__((ext_vector_type(4))) float f32x4;

__device__ __forceinline__ half2v pkrtz(float a, float b) {
    return __builtin_bit_cast(half2v, __builtin_amdgcn_cvt_pkrtz(a, b));
}

__device__ __forceinline__ void gload_lds16(const void* g, void* l) {
    __builtin_amdgcn_global_load_lds(
        (const __attribute__((address_space(1))) unsigned int*)g,
        (__attribute__((address_space(3))) unsigned int*)l, 16, 0, 0);
}

// ================= prep: vemb->f16 | Wv^T->f16 | Wo^T->f16 | Wksum =================
__global__ __launch_bounds__(256) void prep_kernel(const float* __restrict__ vemb,
                                                   const float* __restrict__ Wv,
                                                   const float* __restrict__ Wo,
                                                   const float* __restrict__ Wk,
                                                   const float* __restrict__ bk,
                                                   _Float16* __restrict__ Ab16,
                                                   _Float16* __restrict__ Wvt,
                                                   _Float16* __restrict__ Wot,
                                                   float* __restrict__ Wksum,
                                                   float* __restrict__ bksum) {
    __shared__ float tl[32][33];
    int blk = blockIdx.x, tid = threadIdx.x;
    if (blk < 768) {
        int i4 = (blk * 256 + tid) * 4;
        float4 v = make_float4(0.f, 0.f, 0.f, 0.f);
        if (i4 < S_LEN * D_LLM) v = *(const float4*)(vemb + i4);
        short4 o;
        o.x = __builtin_bit_cast(short, (_Float16)v.x);
        o.y = __builtin_bit_cast(short, (_Float16)v.y);
        o.z = __builtin_bit_cast(short, (_Float16)v.z);
        o.w = __builtin_bit_cast(short, (_Float16)v.w);
        *(short4*)(Ab16 + i4) = o;
    } else if (blk < 1536) {
        int tau = blk - 768;
        int k0 = (tau % 24) * 32, n0 = (tau / 24) * 32;
        int tx = tid & 31, ty = tid >> 5;
        #pragma unroll
        for (int p = 0; p < 4; ++p)
            tl[ty + p * 8][tx] = Wv[(size_t)(k0 + ty + p * 8) * DKH + n0 + tx];
        __syncthreads();
        #pragma unroll
        for (int p = 0; p < 4; ++p)
            Wvt[(size_t)(n0 + ty + p * 8) * D_LLM + k0 + tx] = (_Float16)tl[tx][ty + p * 8];
    } else if (blk < 2304) {
        int tau = blk - 1536;
        int k0 = (tau & 31) * 32, n0 = (tau >> 5) * 32;
        int tx = tid & 31, ty = tid >> 5;
        #pragma unroll
        for (int p = 0; p < 4; ++p)
            tl[ty + p * 8][tx] = Wo[(size_t)(k0 + ty + p * 8) * D_LLM + n0 + tx];
        __syncthreads();
        #pragma unroll
        for (int p = 0; p < 4; ++p)
            Wot[(size_t)(n0 + ty + p * 8) * DKH + k0 + tx] = (_Float16)tl[tx][ty + p * 8];
    } else {
        int blk2 = blk - 2304;
        int w = tid >> 6, lane = tid & 63;
        if (blk2 < 192) {
            int d = blk2 * 4 + w;
            const float* p = Wk + (size_t)d * DKH + lane * 16;
            float s = 0.f;
            #pragma unroll
            for (int i = 0; i < 4; ++i) {
                float4 v = *(const float4*)(p + i * 4);
                s += v.x + v.y + v.z + v.w;
            }
            s += __shfl_down(s, 4);
            s += __shfl_down(s, 2);
            s += __shfl_down(s, 1);
            if ((lane & 7) == 0) Wksum[d * NH + (lane >> 3)] = s;
        } else if (w == 0) {
            const float* p = bk + lane * 16;
            float s = 0.f;
            #pragma unroll
            for (int i = 0; i < 4; ++i) {
                float4 v = *(const float4*)(p + i * 4);
                s += v.x + v.y + v.z + v.w;
            }
            s += __shfl_down(s, 4);
            s += __shfl_down(s, 2);
            s += __shfl_down(s, 1);
            if ((lane & 7) == 0) bksum[lane >> 3] = s;
        }
    }
}

// ================= merged: ksum (blocks 0-255) + vproj (blocks 256-511) =================
__global__ __launch_bounds__(256) void kv_kernel(const float* __restrict__ src,
                                                 const float* __restrict__ Wksum,
                                                 const float* __restrict__ bksum,
                                                 float* __restrict__ Kpad,
                                                 const _Float16* __restrict__ A,
                                                 const _Float16* __restrict__ Bt,
                                                 const float* __restrict__ bias,
                                                 _Float16* __restrict__ Vt) {
    __shared__ _Float16 VAs[2][2048];
    __shared__ _Float16 VBs[2][2048];
    int tid = threadIdx.x;
    if (blockIdx.x < 256) {
        // ---- ksum: Kpad[h][s] = (src[s,:].Wksum[:,h] + bksum[h]) * SCALE_EXP2 ----
        int w = tid >> 6, lane = tid & 63;
        int s = blockIdx.x * 4 + w;
        if (s >= S_LEN) {
            if (lane < 8) Kpad[lane * S_PAD + s] = 0.f;
            return;
        }
        const float* sp = src + (size_t)s * D_LLM + lane * 12;
        float xv[12];
        ((float4*)xv)[0] = *(const float4*)(sp);
        ((float4*)xv)[1] = *(const float4*)(sp + 4);
        ((float4*)xv)[2] = *(const float4*)(sp + 8);
        float a[8] = {0.f, 0.f, 0.f, 0.f, 0.f, 0.f, 0.f, 0.f};
        const float* wp = Wksum + lane * 12 * NH;
        #pragma unroll
        for (int i = 0; i < 12; ++i) {
            float4 wa = *(const float4*)(wp + i * 8);
            float4 wb = *(const float4*)(wp + i * 8 + 4);
            a[0] = fmaf(xv[i], wa.x, a[0]); a[1] = fmaf(xv[i], wa.y, a[1]);
            a[2] = fmaf(xv[i], wa.z, a[2]); a[3] = fmaf(xv[i], wa.w, a[3]);
            a[4] = fmaf(xv[i], wb.x, a[4]); a[5] = fmaf(xv[i], wb.y, a[5]);
            a[6] = fmaf(xv[i], wb.z, a[6]); a[7] = fmaf(xv[i], wb.w, a[7]);
        }
        #pragma unroll
        for (int off = 32; off > 0; off >>= 1) {
            #pragma unroll
            for (int hh = 0; hh < 8; ++hh) a[hh] += __shfl_xor(a[hh], off);
        }
        #pragma unroll
        for (int hh = 0; hh < 8; ++hh)
            if (lane == hh) Kpad[hh * S_PAD + s] = (a[hh] + bksum[hh]) * SCALE_EXP2;
        return;
    }
    // ---- vproj: 64x64 tiles ----
    int b2 = blockIdx.x - 256;
    int w = tid >> 6, lane = tid & 63;
    int bm0 = (b2 >> 4) * 64, bn0 = (b2 & 15) * 64;
    int lrow = tid >> 2, lcol = (tid & 3) * 8;
    const _Float16* ga = A + (size_t)(bm0 + lrow) * D_LLM + lcol;
    const _Float16* gb = Bt + (size_t)(bn0 + lrow) * D_LLM + lcol;

    f32x4 acc[2][2];
    #pragma unroll
    for (int m = 0; m < 2; ++m)
        #pragma unroll
        for (int n = 0; n < 2; ++n) acc[m][n] = (f32x4){0.f, 0.f, 0.f, 0.f};
    int sgrp = (lane >> 4) << 3;
    int arow = (w >> 1) * 32 + (lane & 15);
    int brow = (w & 1) * 32 + (lane & 15);

#define VSTAGE(buf, k0) do { \
        gload_lds16(ga + (k0), (char*)&VAs[buf][0] + w * 1024); \
        gload_lds16(gb + (k0), (char*)&VBs[buf][0] + w * 1024); } while (0)

    VSTAGE(0, 0);
    __syncthreads();
    #pragma unroll 2
    for (int tt = 0; tt < 24; ++tt) {
        int cur = tt & 1;
        if (tt < 23) VSTAGE(cur ^ 1, (tt + 1) * 32);
        const _Float16* Ac = &VAs[cur][0];
        const _Float16* Bc = &VBs[cur][0];
        half8 af[2], bf[2];
        #pragma unroll
        for (int m = 0; m < 2; ++m) af[m] = *(const half8*)(Ac + (arow + m * 16) * 32 + sgrp);
        #pragma unroll
        for (int n = 0; n < 2; ++n) bf[n] = *(const half8*)(Bc + (brow + n * 16) * 32 + sgrp);
        __builtin_amdgcn_s_setprio(1);
        #pragma unroll
        for (int m = 0; m < 2; ++m)
            #pragma unroll
            for (int n = 0; n < 2; ++n)
                acc[m][n] = __builtin_amdgcn_mfma_f32_16x16x32_f16(af[m], bf[n], acc[m][n], 0, 0, 0);
        __builtin_amdgcn_s_setprio(0);
        __syncthreads();
    }
#undef VSTAGE

    int rowoff = (lane >> 4) << 2;
    #pragma unroll
    for (int m = 0; m < 2; ++m) {
        #pragma unroll
        for (int n = 0; n < 2; ++n) {
            int c = bn0 + (w & 1) * 32 + n * 16 + (lane & 15);
            float b = bias[c];
            #pragma unroll
            for (int q = 0; q < 4; ++q) {
                int srow = bm0 + (w >> 1) * 32 + m * 16 + rowoff + q;
                float val = (srow < S_LEN) ? acc[m][n][q] + b : 0.f;
                Vt[(size_t)c * S_PAD + srow] = (_Float16)val;
            }
        }
    }
}

// ================= fused softmax + PV: 3-buffer, 1 barrier/chunk, LDS-resident K-row =================
__device__ __forceinline__ void compute_afr(const float* kq, float x0, float x1,
                                            float nm0, float nm1, half8& o0, half8& o1) {
    float4 a = *(const float4*)kq;        // ds_read_b128 (LDS)
    float4 b = *(const float4*)(kq + 4);
    float kv[8] = {a.x, a.y, a.z, a.w, b.x, b.y, b.z, b.w};
    union { half8 v; half2v h[4]; } u0, u1;
    #pragma unroll
    for (int j = 0; j < 4; ++j) {
        float w00 = __builtin_amdgcn_exp2f(fmaf(x0, kv[2 * j], nm0));
        float w01 = __builtin_amdgcn_exp2f(fmaf(x0, kv[2 * j + 1], nm0));
        u0.h[j] = pkrtz(w00, w01);
        float w10 = __builtin_amdgcn_exp2f(fmaf(x1, kv[2 * j], nm1));
        float w11 = __builtin_amdgcn_exp2f(fmaf(x1, kv[2 * j + 1], nm1));
        u1.h[j] = pkrtz(w10, w11);
    }
    o0 = u0.v; o1 = u1.v;
}

__global__ __launch_bounds__(256) void attn_mfma_kernel(const float* __restrict__ ts,
                                                        const float* __restrict__ Kpad,
                                                        const _Float16* __restrict__ Vt,
                                                        _Float16* __restrict__ attB) {
    __shared__ _Float16 Vs[3][8192];   // 3 x 16KB chunks (64 s x 128 e, XOR-swizzled rows)
    __shared__ float Krow[1024];       // this head's scaled K row (4KB)
    __shared__ float red[8];
    const int tid = threadIdx.x;
    const int lane = tid & 63, w = tid >> 6;
    const int h = blockIdx.y;
    const int m0 = (blockIdx.x * 4 + w) * 32;
    const int l15 = lane & 15, q = lane >> 4;

    const int erow = w * 8 + (lane >> 3);
    const int sgl = ((lane & 7) ^ (lane >> 3)) * 8;
    const _Float16* gsrc = Vt + (size_t)(h * DK + erow) * S_PAD + sgl;
    const float* kg = Kpad + h * S_PAD;

    // issue Krow stage first (oldest), then V chunks 0,1
    gload_lds16(kg + w * 256 + lane * 4, (char*)Krow + w * 1024);
    #pragma unroll
    for (int i = 0; i < 4; ++i)
        gload_lds16(gsrc + (size_t)(i * 32) * S_PAD, (char*)&Vs[0][0] + i * 4096 + w * 1024);
    #pragma unroll
    for (int i = 0; i < 4; ++i)
        gload_lds16(gsrc + (size_t)(i * 32) * S_PAD + 64, (char*)&Vs[1][0] + i * 4096 + w * 1024);

    float x0, x1;
    {
        int m = m0 + l15;
        int rr = m / T_LEN;
        float v = ts[((size_t)(rr >> 4) * T_LEN + (m % T_LEN)) * N_VARS + (rr & 15)];
        x0 = (v != v) ? 0.f : v;
        m = m0 + 16 + l15;
        rr = m / T_LEN;
        v = ts[((size_t)(rr >> 4) * T_LEN + (m % T_LEN)) * N_VARS + (rr & 15)];
        x1 = (v != v) ? 0.f : v;
    }

    asm volatile("s_waitcnt vmcnt(8)" ::: "memory");   // Krow landed (V chunks may still fly)
    __builtin_amdgcn_sched_barrier(0);
    __builtin_amdgcn_s_barrier();

    // per-head min/max from LDS row (s<1000 only; pads are 0)
    float mn, mx;
    {
        float4 k4 = *(const float4*)&Krow[tid * 4];
        if (tid < 250) {
            mx = fmaxf(fmaxf(k4.x, k4.y), fmaxf(k4.z, k4.w));
            mn = fminf(fminf(k4.x, k4.y), fminf(k4.z, k4.w));
        } else { mx = -3e38f; mn = 3e38f; }
        #pragma unroll
        for (int off = 32; off > 0; off >>= 1) {
            mx = fmaxf(mx, __shfl_xor(mx, off));
            mn = fminf(mn, __shfl_xor(mn, off));
        }
        if (lane == 0) { red[w * 2] = mn; red[w * 2 + 1] = mx; }
        asm volatile("s_waitcnt lgkmcnt(0)" ::: "memory");
        __builtin_amdgcn_sched_barrier(0);
        __builtin_amdgcn_s_barrier();
        mn = fminf(fminf(red[0], red[2]), fminf(red[4], red[6]));
        mx = fmaxf(fmaxf(red[1], red[3]), fmaxf(red[5], red[7]));
    }

    float nm0 = -((x0 >= 0.f) ? x0 * mx : x0 * mn);
    float nm1 = -((x1 >= 0.f) ? x1 * mx : x1 * mn);
    float wpadf0, wpadf1;
    {
        half2v p0 = pkrtz(__builtin_amdgcn_exp2f(nm0), 0.f);
        half2v p1 = pkrtz(__builtin_amdgcn_exp2f(nm1), 0.f);
        wpadf0 = (float)p0[0];
        wpadf1 = (float)p1[0];
    }

    f32x4 acc0[8], acc1[8];
    #pragma unroll
    for (int e = 0; e < 8; ++e) {
        acc0[e] = (f32x4){0.f, 0.f, 0.f, 0.f};
        acc1[e] = (f32x4){0.f, 0.f, 0.f, 0.f};
    }
    f32x4 accd0 = (f32x4){0.f, 0.f, 0.f, 0.f};
    f32x4 accd1 = (f32x4){0.f, 0.f, 0.f, 0.f};
    half8 ones;
    #pragma unroll
    for (int j = 0; j < 8; ++j) ones[j] = (_Float16)1.0f;

    const float* kvp = Krow + q * 8;   // LDS — P-gen never touches vmcnt
    half8 afrA0, afrA1, afrB0, afrB1;
    compute_afr(kvp, x0, x1, nm0, nm1, afrA0, afrA1);

    const int bofs0 = l15 * 128 + ((q * 16) ^ ((l15 & 7) << 4));
    const int bofs1 = l15 * 128 + ((64 + q * 16) ^ ((l15 & 7) << 4));

#define PVSTEP(AF0, AF1, BOFS) do { \
        __builtin_amdgcn_s_setprio(1); \
        _Pragma("unroll") \
        for (int e = 0; e < 8; ++e) { \
            half8 bfv = *(const half8*)(cb + e * 2048 + (BOFS)); \
            acc0[e] = __builtin_amdgcn_mfma_f32_16x16x32_f16(AF0, bfv, acc0[e], 0, 0, 0); \
            acc1[e] = __builtin_amdgcn_mfma_f32_16x16x32_f16(AF1, bfv, acc1[e], 0, 0, 0); \
        } \
        accd0 = __builtin_amdgcn_mfma_f32_16x16x32_f16(AF0, ones, accd0, 0, 0, 0); \
        accd1 = __builtin_amdgcn_mfma_f32_16x16x32_f16(AF1, ones, accd1, 0, 0, 0); \
        __builtin_amdgcn_s_setprio(0); } while (0)

    #pragma unroll
    for (int kt = 0; kt < 16; ++kt) {
        // chunk kt landed? (chunks kt+1, kt+2 may stay in flight — never drain mid-loop)
        if (kt == 15) asm volatile("s_waitcnt vmcnt(0)" ::: "memory");
        else         asm volatile("s_waitcnt vmcnt(4)" ::: "memory");
        __builtin_amdgcn_sched_barrier(0);
        __builtin_amdgcn_s_barrier();    // publishes chunk kt; licenses overwrite of buf (kt+2)%3
        if (kt < 14) {
            char* d = (char*)&Vs[0][0] + ((kt + 2) % 3) * 16384 + w * 1024;
            #pragma unroll
            for (int i = 0; i < 4; ++i)
                gload_lds16(gsrc + (size_t)(i * 32) * S_PAD + (kt + 2) * 64, d + i * 4096);
        }
        const char* cb = (const char*)&Vs[0][0] + (kt % 3) * 16384;
        compute_afr(kvp + kt * 64 + 32, x0, x1, nm0, nm1, afrB0, afrB1);
        PVSTEP(afrA0, afrA1, bofs0);
        if (kt < 15) compute_afr(kvp + (kt + 1) * 64, x0, x1, nm0, nm1, afrA0, afrA1);
        PVSTEP(afrB0, afrB1, bofs1);
    }
#undef PVSTEP

    // epilogue: den = rowsum - 24 * wpad(row)
    int rowoff = q << 2;
    #pragma unroll
    for (int r = 0; r < 2; ++r) {
        #pragma unroll
        for (int qq = 0; qq < 4; ++qq) {
            float wp = __shfl(r ? wpadf1 : wpadf0, rowoff + qq);
            float den = (r ? accd1[qq] : accd0[qq]) - 24.f * wp;
            float inv = 1.f / den;
            int mrow = m0 + r * 16 + rowoff + qq;
            _Float16* op = attB + (size_t)mrow * DKH + h * DK + l15;
            #pragma unroll
            for (int e = 0; e < 8; ++e)
                op[e * 16] = (_Float16)((r ? acc1[e][qq] : acc0[e][qq]) * inv);
        }
    }
}

// ================= out projection: 128x96 tiles, 3-buffer, 1 barrier/k-step =================
__global__ __launch_bounds__(256) void outproj_kernel(const _Float16* __restrict__ A,
                                                      const _Float16* __restrict__ Bt,
                                                      const float* __restrict__ bo,
                                                      float* __restrict__ C) {
    __shared__ _Float16 As[3][4096];   // 3 x 8KB
    __shared__ _Float16 Bs[3][3072];   // 3 x 6KB
    int wg = blockIdx.x;
    wg = (wg & 7) * 96 + (wg >> 3);            // bijective XCD chunking (768 % 8 == 0)
    int bx = wg & 7, by = wg >> 3;
    int t = threadIdx.x, w = t >> 6, lane = t & 63;
    int bm0 = by * 128, bn0 = bx * 96;
    int lrow = t >> 2, lcol = (t & 3) * 8;
    const _Float16* ga0 = A + (size_t)(bm0 + lrow) * DKH + lcol;
    const _Float16* ga1 = ga0 + (size_t)64 * DKH;
    const _Float16* gb0 = Bt + (size_t)(bn0 + lrow) * DKH + lcol;
    const _Float16* gb1 = gb0 + (size_t)64 * DKH;   // rows 64..95: waves 0-1 only

    f32x4 acc[4][3];
    #pragma unroll
    for (int m = 0; m < 4; ++m)
        #pragma unroll
        for (int n = 0; n < 3; ++n) acc[m][n] = (f32x4){0.f, 0.f, 0.f, 0.f};

    int sgrp = (lane >> 4) << 3;
    int arow = (w >> 1) * 64 + (lane & 15);
    int brow = (w & 1) * 48 + (lane & 15);

#define OSTAGE(bi, k0) do { \
        gload_lds16(ga0 + (k0), (char*)&As[bi][0] + w * 1024); \
        gload_lds16(ga1 + (k0), (char*)&As[bi][0] + 4096 + w * 1024); \
        gload_lds16(gb0 + (k0), (char*)&Bs[bi][0] + w * 1024); \
        if (w < 2) gload_lds16(gb1 + (k0), (char*)&Bs[bi][0] + 4096 + w * 1024); } while (0)

    OSTAGE(0, 0);
    OSTAGE(1, 32);
    #pragma unroll
    for (int kt = 0; kt < 32; ++kt) {
        if (kt == 31)   asm volatile("s_waitcnt vmcnt(0)" ::: "memory");
        else if (w < 2) asm volatile("s_waitcnt vmcnt(4)" ::: "memory");
        else            asm volatile("s_waitcnt vmcnt(3)" ::: "memory");
        __builtin_amdgcn_sched_barrier(0);
        __builtin_amdgcn_s_barrier();
        if (kt < 30) OSTAGE((kt + 2) % 3, (kt + 2) * 32);
        const _Float16* Ac = &As[kt % 3][0];
        const _Float16* Bc = &Bs[kt % 3][0];
        half8 af[4], bf[3];
        #pragma unroll
        for (int m = 0; m < 4; ++m) af[m] = *(const half8*)(Ac + (arow + m * 16) * 32 + sgrp);
        #pragma unroll
        for (int n = 0; n < 3; ++n) bf[n] = *(const half8*)(Bc + (brow + n * 16) * 32 + sgrp);
        __builtin_amdgcn_s_setprio(1);
        #pragma unroll
        for (int m = 0; m < 4; ++m)
            #pragma unroll
            for (int n = 0; n < 3; ++n)
                acc[m][n] = __builtin_amdgcn_mfma_f32_16x16x32_f16(af[m], bf[n], acc[m][n], 0, 0, 0);
        __builtin_amdgcn_s_setprio(0);
    }
#undef OSTAGE

    int rowoff = (lane >> 4) << 2;
    #pragma unroll
    for (int m = 0; m < 4; ++m) {
        #pragma unroll
        for (int n = 0; n < 3; ++n) {
            int col = bn0 + (w & 1) * 48 + n * 16 + (lane & 15);
            float b = bo[col];
            #pragma unroll
            for (int q = 0; q < 4; ++q) {
                int row = bm0 + (w >> 1) * 64 + m * 16 + rowoff + q;
                C[(size_t)row * D_LLM + col] = acc[m][n][q] + b;
            }
        }
    }
}

extern "C" void kernel_launch(void* const* d_in, const int* in_sizes, int n_in,
                              void* d_out, int out_size, void* d_ws, size_t ws_size,
                              hipStream_t stream) {
    const float* ts   = (const float*)d_in[0];
    const float* src  = (const float*)d_in[1];
    const float* vemb = (const float*)d_in[2];
    const float* Wk   = (const float*)d_in[3];
    const float* bk   = (const float*)d_in[4];
    const float* Wv   = (const float*)d_in[5];
    const float* bv   = (const float*)d_in[6];
    const float* Wo   = (const float*)d_in[7];
    const float* bo   = (const float*)d_in[8];
    float* out = (float*)d_out;

    // workspace layout (float offsets, 16B aligned)
    float* ws = (float*)d_ws;
    float* Kpad   = ws;                               // 8192 f
    float* Wksum  = ws + 8192;                        // 6144 f
    float* bksum  = ws + 14336;                       // 16 f
    _Float16* Vt   = (_Float16*)(ws + 14592);         // 1024*1024 f16
    _Float16* Wot  = (_Float16*)(ws + 540672);        // 768*1024 f16
    _Float16* attB = (_Float16*)(ws + 936960);        // 12288*1024 f16
    // vproj prep buffers alias attB region (dead before attn writes attB)
    _Float16* Ab16 = (_Float16*)(ws + 936960);        // 1024*768 f16
    _Float16* Wvt  = (_Float16*)(ws + 1330176);       // 1024*768 f16

    // 1) prep: vemb->f16, Wv^T, Wo^T, Wksum/bksum
    prep_kernel<<<2497, 256, 0, stream>>>(vemb, Wv, Wo, Wk, bk, Ab16, Wvt, Wot, Wksum, bksum);
    // 2) merged ksum + vproj
    kv_kernel<<<512, 256, 0, stream>>>(src, Wksum, bksum, Kpad, Ab16, Wvt, bv, Vt);
    // 3) fused softmax + PV (f16 MFMA, 3-buf counted-vmcnt, in-kernel minmax)
    {
        dim3 g(96, NH);
        attn_mfma_kernel<<<g, 256, 0, stream>>>(ts, Kpad, Vt, attB);
    }
    // 4) out projection: [12288,1024]@[1024,768] + bo
    outproj_kernel<<<768, 256, 0, stream>>>(attB, Wot, bo, out);
}